// Round 9
// baseline (175.102 us; speedup 1.0000x reference)
//
#include <hip/hip_runtime.h>
#include <math.h>

#define NH 16
#define KD 64
#define DMODEL 1024
#define BATCH 2
#define SEQ 2048
#define MROWS (BATCH*SEQ)

typedef float f32x4 __attribute__((ext_vector_type(4)));
typedef __bf16 bf16x8 __attribute__((ext_vector_type(8)));

__device__ __forceinline__ unsigned short f2bf(float x) {
    union { float f; unsigned u; } a; a.f = x;
    unsigned r = a.u + 0x7fffu + ((a.u >> 16) & 1u);
    return (unsigned short)(r >> 16);
}
__device__ __forceinline__ float bf2f(unsigned short h) {
    union { unsigned u; float f; } a; a.u = ((unsigned)h) << 16; return a.f;
}
__device__ __forceinline__ unsigned cvt_pk_bf16(float lo, float hi) {
    unsigned r;
    asm("v_cvt_pk_bf16_f32 %0, %1, %2" : "=v"(r) : "v"(lo), "v"(hi));
    return r;
}
__device__ __forceinline__ float exp2_hw(float x) {
    float r;
    asm("v_exp_f32 %0, %1" : "=v"(r) : "v"(x));
    return r;
}

__device__ __forceinline__ void gl2lds16(const void* gsrc, void* ldst) {
    __builtin_amdgcn_global_load_lds(
        (const __attribute__((address_space(1))) void*)gsrc,
        (__attribute__((address_space(3))) void*)ldst, 16, 0, 0);
}

// ---------------------------------------------------------------------------
__global__ __launch_bounds__(256) void k_rope_tables(float* __restrict__ sin_t,
                                                     float* __restrict__ cos_t) {
    int idx = blockIdx.x * 256 + threadIdx.x;
    if (idx >= SEQ * 32) return;
    int s = idx >> 5, i = idx & 31;
    float invf = expf((float)(2 * i) * (-logf(10000.0f) / (float)KD));
    float ang = (float)s * invf;
    sin_t[idx] = sinf(ang);
    cos_t[idx] = cosf(ang);
}

// ---------------------------------------------------------------------------
__global__ __launch_bounds__(256) void k_cvt_x(const float* __restrict__ x,
                                               unsigned short* __restrict__ xh) {
    int idx = blockIdx.x * 256 + threadIdx.x;
    float4 v = reinterpret_cast<const float4*>(x)[idx];
    ushort4 h;
    h.x = f2bf(v.x); h.y = f2bf(v.y); h.z = f2bf(v.z); h.w = f2bf(v.w);
    reinterpret_cast<ushort4*>(xh)[idx] = h;
}

// ---------------------------------------------------------------------------
__global__ __launch_bounds__(256) void k_cvt_w4(const float* __restrict__ W0,
                                                const float* __restrict__ W1,
                                                const float* __restrict__ W2,
                                                const float* __restrict__ W3,
                                                unsigned short* __restrict__ Th,
                                                unsigned short* __restrict__ Tl) {
    __shared__ float L[64][65];
    const int tid = threadIdx.x;
    const int n0 = blockIdx.x * 64, k0 = blockIdx.y * 64;
    const int z = blockIdx.z;
    const float* W = (z == 0) ? W0 : (z == 1) ? W1 : (z == 2) ? W2 : W3;
    const size_t zoff = (size_t)z * DMODEL * DMODEL;
#pragma unroll
    for (int it = 0; it < 4; ++it) {
        int idx = tid + it * 256;
        int r = idx >> 4;
        int c4 = (idx & 15) * 4;
        float4 v = *reinterpret_cast<const float4*>(&W[(size_t)(k0 + r) * DMODEL + n0 + c4]);
        L[r][c4 + 0] = v.x; L[r][c4 + 1] = v.y; L[r][c4 + 2] = v.z; L[r][c4 + 3] = v.w;
    }
    __syncthreads();
    int rn = tid >> 2;
    int ks = (tid & 3) * 16;
#pragma unroll
    for (int g = 0; g < 4; ++g) {
        ushort4 h, l;
        float v0 = L[ks + g * 4 + 0][rn];
        float v1 = L[ks + g * 4 + 1][rn];
        float v2 = L[ks + g * 4 + 2][rn];
        float v3 = L[ks + g * 4 + 3][rn];
        h.x = f2bf(v0); l.x = f2bf(v0 - bf2f(h.x));
        h.y = f2bf(v1); l.y = f2bf(v1 - bf2f(h.y));
        h.z = f2bf(v2); l.z = f2bf(v2 - bf2f(h.z));
        h.w = f2bf(v3); l.w = f2bf(v3 - bf2f(h.w));
        size_t o = zoff + (size_t)(n0 + rn) * DMODEL + k0 + ks + g * 4;
        *reinterpret_cast<ushort4*>(&Th[o]) = h;
        *reinterpret_cast<ushort4*>(&Tl[o]) = l;
    }
}

// ---------------------------------------------------------------------------
// QKV GEMM: 2-MFMA split (ah·bl + ah·bh), double-buffered, 1 barrier/kt.
// Tile 128x64, BK=64, 4 waves. LDS 64KB -> 2 blocks/CU (= grid cap).
// MODE 1: RoPE*(0.125*log2e) -> bf16 (Q); MODE 2: RoPE -> bf16 (K);
// MODE 3: plain -> bf16 [b,h,d,s] (V^T).
// ---------------------------------------------------------------------------
template<int MODE>
__global__ __launch_bounds__(256) void k_mgemm_q(const unsigned short* __restrict__ Ah_g,
                                                 const unsigned short* __restrict__ Bh_g,
                                                 const unsigned short* __restrict__ Bl_g,
                                                 const float* __restrict__ bias,
                                                 unsigned short* __restrict__ Ohi,
                                                 const float* __restrict__ sin_t,
                                                 const float* __restrict__ cos_t) {
    __shared__ unsigned short Ah[2][128 * 64];
    __shared__ unsigned short Bh[2][64 * 64];
    __shared__ unsigned short Bl[2][64 * 64];
    const int tid = threadIdx.x;
    const int lane = tid & 63;
    const int w = tid >> 6;

    int bid = blockIdx.x;
    int wg = (bid & 7) * 64 + (bid >> 3);
    const int m0 = (wg >> 4) * 128;
    const int n0 = (wg & 15) * 64;

    size_t a_goff[4]; int a_ldst[4];
#pragma unroll
    for (int it = 0; it < 4; ++it) {
        int off = it * 4096 + w * 1024 + lane * 16;
        int row = off >> 7;
        int pg = (off >> 4) & 7;
        int lg = pg ^ (row & 7);
        a_goff[it] = (size_t)(m0 + row) * DMODEL + lg * 8;
        a_ldst[it] = it * 2048 + w * 512;
    }
    size_t b_goff[2]; int b_ldst[2];
#pragma unroll
    for (int it = 0; it < 2; ++it) {
        int off = it * 4096 + w * 1024 + lane * 16;
        int row = off >> 7;
        int pg = (off >> 4) & 7;
        int lg = pg ^ (row & 7);
        b_goff[it] = (size_t)(n0 + row) * DMODEL + lg * 8;
        b_ldst[it] = it * 2048 + w * 512;
    }

    int aoff[2][2], boff[4][2];
#pragma unroll
    for (int mf = 0; mf < 2; ++mf)
#pragma unroll
        for (int ks = 0; ks < 2; ++ks) {
            int row = w * 32 + mf * 16 + (lane & 15);
            int g = ks * 4 + (lane >> 4);
            aoff[mf][ks] = row * 64 + ((g ^ (row & 7)) * 8);
        }
#pragma unroll
    for (int nf = 0; nf < 4; ++nf)
#pragma unroll
        for (int ks = 0; ks < 2; ++ks) {
            int row = nf * 16 + (lane & 15);
            int g = ks * 4 + (lane >> 4);
            boff[nf][ks] = row * 64 + ((g ^ (row & 7)) * 8);
        }

    f32x4 acc[2][4];
#pragma unroll
    for (int mf = 0; mf < 2; ++mf)
#pragma unroll
        for (int nf = 0; nf < 4; ++nf) acc[mf][nf] = (f32x4){0.f, 0.f, 0.f, 0.f};

#define STAGEG(BUF, KT) do {                                                  \
        int k0_ = (KT) * 64;                                                  \
        gl2lds16(Ah_g + a_goff[0] + k0_, &Ah[BUF][a_ldst[0]]);                \
        gl2lds16(Ah_g + a_goff[1] + k0_, &Ah[BUF][a_ldst[1]]);                \
        gl2lds16(Ah_g + a_goff[2] + k0_, &Ah[BUF][a_ldst[2]]);                \
        gl2lds16(Ah_g + a_goff[3] + k0_, &Ah[BUF][a_ldst[3]]);                \
        gl2lds16(Bh_g + b_goff[0] + k0_, &Bh[BUF][b_ldst[0]]);                \
        gl2lds16(Bh_g + b_goff[1] + k0_, &Bh[BUF][b_ldst[1]]);                \
        gl2lds16(Bl_g + b_goff[0] + k0_, &Bl[BUF][b_ldst[0]]);                \
        gl2lds16(Bl_g + b_goff[1] + k0_, &Bl[BUF][b_ldst[1]]);                \
    } while (0)

    STAGEG(0, 0);

    for (int kt = 0; kt < 16; ++kt) {
        const int cur = kt & 1;
        asm volatile("s_waitcnt vmcnt(0)" ::: "memory");
        __builtin_amdgcn_s_barrier();
        if (kt < 15) STAGEG(cur ^ 1, kt + 1);
#pragma unroll
        for (int ks = 0; ks < 2; ++ks) {
            bf16x8 ah[2], bh[4], bl[4];
#pragma unroll
            for (int mf = 0; mf < 2; ++mf)
                ah[mf] = *reinterpret_cast<const bf16x8*>(&Ah[cur][aoff[mf][ks]]);
#pragma unroll
            for (int nf = 0; nf < 4; ++nf) {
                bh[nf] = *reinterpret_cast<const bf16x8*>(&Bh[cur][boff[nf][ks]]);
                bl[nf] = *reinterpret_cast<const bf16x8*>(&Bl[cur][boff[nf][ks]]);
            }
#pragma unroll
            for (int mf = 0; mf < 2; ++mf)
#pragma unroll
                for (int nf = 0; nf < 4; ++nf) {
                    acc[mf][nf] = __builtin_amdgcn_mfma_f32_16x16x32_bf16(ah[mf], bl[nf], acc[mf][nf], 0, 0, 0);
                    acc[mf][nf] = __builtin_amdgcn_mfma_f32_16x16x32_bf16(ah[mf], bh[nf], acc[mf][nf], 0, 0, 0);
                }
        }
    }
#undef STAGEG

    const int c = lane & 15;
    const int rq = lane >> 4;
    float bv[4];
#pragma unroll
    for (int nf = 0; nf < 4; ++nf) bv[nf] = bias[n0 + nf * 16 + c];

#pragma unroll
    for (int mf = 0; mf < 2; ++mf) {
        int mbase = m0 + w * 32 + mf * 16 + rq * 4;
        if (MODE == 1 || MODE == 2) {
#pragma unroll
            for (int r = 0; r < 4; ++r) {
                int m = mbase + r;
                int srow = m & (SEQ - 1);
                float x0 = acc[mf][0][r] + bv[0];
                float x1 = acc[mf][1][r] + bv[1];
                float x2 = acc[mf][2][r] + bv[2];
                float x3 = acc[mf][3][r] + bv[3];
                float s0 = sin_t[srow * 32 + c],      c0 = cos_t[srow * 32 + c];
                float s1 = sin_t[srow * 32 + 16 + c], c1 = cos_t[srow * 32 + 16 + c];
                float o0 = c0 * x0 - s0 * x2;
                float o2 = s0 * x0 + c0 * x2;
                float o1 = c1 * x1 - s1 * x3;
                float o3 = s1 * x1 + c1 * x3;
                if (MODE == 1) {
                    const float qs = 0.18033688011112042f;   // 0.125*log2(e)
                    o0 *= qs; o1 *= qs; o2 *= qs; o3 *= qs;
                }
                float ov[4] = { o0, o1, o2, o3 };
                size_t base = (size_t)m * DMODEL + n0 + c;
#pragma unroll
                for (int nf = 0; nf < 4; ++nf)
                    Ohi[base + nf * 16] = f2bf(ov[nf]);
            }
        } else {   // MODE 3: V^T [b,h,d,s]
            int bb = mbase >> 11;
            int s = mbase & (SEQ - 1);
            int h = n0 >> 6;
#pragma unroll
            for (int nf = 0; nf < 4; ++nf) {
                ushort4 h4;
                float v0 = acc[mf][nf][0] + bv[nf];
                float v1 = acc[mf][nf][1] + bv[nf];
                float v2 = acc[mf][nf][2] + bv[nf];
                float v3 = acc[mf][nf][3] + bv[nf];
                h4.x = f2bf(v0); h4.y = f2bf(v1); h4.z = f2bf(v2); h4.w = f2bf(v3);
                int d = nf * 16 + c;
                size_t o = ((size_t)((bb * NH + h) * KD + d)) * SEQ + s;
                *reinterpret_cast<ushort4*>(&Ohi[o]) = h4;
            }
        }
    }
}

// ---------------------------------------------------------------------------
// O-projection GEMM: 3-MFMA split (al·bh + ah·bl + ah·bh), 2-barrier,
// single-buffered. fp32 + bias out.
// ---------------------------------------------------------------------------
__global__ __launch_bounds__(256) void k_mgemm_o(const unsigned short* __restrict__ Ah_g,
                                                 const unsigned short* __restrict__ Al_g,
                                                 const unsigned short* __restrict__ Bh_g,
                                                 const unsigned short* __restrict__ Bl_g,
                                                 const float* __restrict__ bias,
                                                 float* __restrict__ Cf) {
    __shared__ unsigned short Ah[128 * 64];
    __shared__ unsigned short Al[128 * 64];
    __shared__ unsigned short Bh[64 * 64];
    __shared__ unsigned short Bl[64 * 64];
    const int tid = threadIdx.x;
    const int lane = tid & 63;
    const int w = tid >> 6;

    int bid = blockIdx.x;
    int wg = (bid & 7) * 64 + (bid >> 3);
    const int m0 = (wg >> 4) * 128;
    const int n0 = (wg & 15) * 64;

    size_t a_goff[4]; int a_ldst[4];
#pragma unroll
    for (int it = 0; it < 4; ++it) {
        int off = it * 4096 + w * 1024 + lane * 16;
        int row = off >> 7;
        int pg = (off >> 4) & 7;
        int lg = pg ^ (row & 7);
        a_goff[it] = (size_t)(m0 + row) * DMODEL + lg * 8;
        a_ldst[it] = it * 2048 + w * 512;
    }
    size_t b_goff[2]; int b_ldst[2];
#pragma unroll
    for (int it = 0; it < 2; ++it) {
        int off = it * 4096 + w * 1024 + lane * 16;
        int row = off >> 7;
        int pg = (off >> 4) & 7;
        int lg = pg ^ (row & 7);
        b_goff[it] = (size_t)(n0 + row) * DMODEL + lg * 8;
        b_ldst[it] = it * 2048 + w * 512;
    }

    int aoff[2][2], boff[4][2];
#pragma unroll
    for (int mf = 0; mf < 2; ++mf)
#pragma unroll
        for (int ks = 0; ks < 2; ++ks) {
            int row = w * 32 + mf * 16 + (lane & 15);
            int g = ks * 4 + (lane >> 4);
            aoff[mf][ks] = row * 64 + ((g ^ (row & 7)) * 8);
        }
#pragma unroll
    for (int nf = 0; nf < 4; ++nf)
#pragma unroll
        for (int ks = 0; ks < 2; ++ks) {
            int row = nf * 16 + (lane & 15);
            int g = ks * 4 + (lane >> 4);
            boff[nf][ks] = row * 64 + ((g ^ (row & 7)) * 8);
        }

    f32x4 acc[2][4];
#pragma unroll
    for (int mf = 0; mf < 2; ++mf)
#pragma unroll
        for (int nf = 0; nf < 4; ++nf) acc[mf][nf] = (f32x4){0.f, 0.f, 0.f, 0.f};

    for (int kt = 0; kt < 16; ++kt) {
        const int k0 = kt * 64;
#pragma unroll
        for (int it = 0; it < 4; ++it) {
            gl2lds16(Ah_g + a_goff[it] + k0, &Ah[a_ldst[it]]);
            gl2lds16(Al_g + a_goff[it] + k0, &Al[a_ldst[it]]);
        }
#pragma unroll
        for (int it = 0; it < 2; ++it) {
            gl2lds16(Bh_g + b_goff[it] + k0, &Bh[b_ldst[it]]);
            gl2lds16(Bl_g + b_goff[it] + k0, &Bl[b_ldst[it]]);
        }
        __syncthreads();
#pragma unroll
        for (int ks = 0; ks < 2; ++ks) {
            bf16x8 ah[2], al[2], bh[4], bl[4];
#pragma unroll
            for (int mf = 0; mf < 2; ++mf) {
                ah[mf] = *reinterpret_cast<const bf16x8*>(&Ah[aoff[mf][ks]]);
                al[mf] = *reinterpret_cast<const bf16x8*>(&Al[aoff[mf][ks]]);
            }
#pragma unroll
            for (int nf = 0; nf < 4; ++nf) {
                bh[nf] = *reinterpret_cast<const bf16x8*>(&Bh[boff[nf][ks]]);
                bl[nf] = *reinterpret_cast<const bf16x8*>(&Bl[boff[nf][ks]]);
            }
#pragma unroll
            for (int mf = 0; mf < 2; ++mf)
#pragma unroll
                for (int nf = 0; nf < 4; ++nf) {
                    acc[mf][nf] = __builtin_amdgcn_mfma_f32_16x16x32_bf16(al[mf], bh[nf], acc[mf][nf], 0, 0, 0);
                    acc[mf][nf] = __builtin_amdgcn_mfma_f32_16x16x32_bf16(ah[mf], bl[nf], acc[mf][nf], 0, 0, 0);
                    acc[mf][nf] = __builtin_amdgcn_mfma_f32_16x16x32_bf16(ah[mf], bh[nf], acc[mf][nf], 0, 0, 0);
                }
        }
        __syncthreads();
    }

    const int c = lane & 15;
    const int rq = lane >> 4;
    float bv[4];
#pragma unroll
    for (int nf = 0; nf < 4; ++nf) bv[nf] = bias[n0 + nf * 16 + c];
#pragma unroll
    for (int mf = 0; mf < 2; ++mf) {
        int mbase = m0 + w * 32 + mf * 16 + rq * 4;
#pragma unroll
        for (int nf = 0; nf < 4; ++nf)
#pragma unroll
            for (int r = 0; r < 4; ++r)
                Cf[(size_t)(mbase + r) * DMODEL + n0 + nf * 16 + c] = acc[mf][nf][r] + bv[nf];
    }
}

// ---------------------------------------------------------------------------
// Flash attention: 64 q-rows/block (1024 blocks), 4 waves (16 rows each),
// KV tiles of 64 double-buffered, ONE barrier per tile.
// Unnormalized softmax p = 2^s, deferred l-reduce, swapped QK^T.
// LDS 40KB -> 4 blocks/CU.
// ---------------------------------------------------------------------------
__global__ __launch_bounds__(256) void k_attn(const unsigned short* __restrict__ qhi,
                                              const unsigned short* __restrict__ khi,
                                              const unsigned short* __restrict__ vthi,
                                              unsigned short* __restrict__ ch,
                                              unsigned short* __restrict__ cl) {
    __shared__ unsigned short Kh[2][64 * 64];
    __shared__ unsigned short Vh[2][64 * 64];   // [d][t]
    __shared__ unsigned short Ps[4][16 * 64];

    const int tid  = threadIdx.x;
    const int lane = tid & 63;
    const int w    = tid >> 6;

    int bid = blockIdx.x;
    int wg  = (bid & 7) * 128 + (bid >> 3);    // 1024 blocks, 8 XCD chunks
    const int qt = wg & 31;
    const int h  = (wg >> 5) & 15;
    const int b  = wg >> 9;
    const int q0 = qt * 64;

    // Q fragments (bf16, pre-scaled by 0.125*log2e); wave owns 16 q-rows
    bf16x8 qf[2];
#pragma unroll
    for (int ks = 0; ks < 2; ++ks) {
        int row = q0 + w * 16 + (lane & 15);
        int d = ks * 32 + (lane >> 4) * 8;
        qf[ks] = *reinterpret_cast<const bf16x8*>(
            qhi + ((size_t)(b * SEQ + row) * NH + h) * KD + d);
    }

    size_t gK[2], gV[2]; int ld_[2];
#pragma unroll
    for (int it = 0; it < 2; ++it) {
        int off = it * 4096 + tid * 16;
        int row = off >> 7;
        int pg = (off >> 4) & 7;
        int lg = pg ^ (row & 7);
        gK[it] = ((size_t)(b * SEQ + row) * NH + h) * KD + lg * 8;
        gV[it] = ((size_t)(b * NH + h) * KD + row) * SEQ + lg * 8;
        ld_[it] = it * 2048 + w * 512;
    }

    f32x4 acc[4];
    float l_part = 0.f;
#pragma unroll
    for (int nf = 0; nf < 4; ++nf) acc[nf] = (f32x4){0.f, 0.f, 0.f, 0.f};

#define STAGE(BUF, TT) do {                                                  \
        size_t kadv = (size_t)(TT) * 64 * NH * KD;                           \
        size_t vadv = (size_t)(TT) * 64;                                     \
        gl2lds16(khi  + gK[0] + kadv, &Kh[BUF][ld_[0]]);                     \
        gl2lds16(khi  + gK[1] + kadv, &Kh[BUF][ld_[1]]);                     \
        gl2lds16(vthi + gV[0] + vadv, &Vh[BUF][ld_[0]]);                     \
        gl2lds16(vthi + gV[1] + vadv, &Vh[BUF][ld_[1]]);                     \
    } while (0)

    STAGE(0, 0);

    for (int t = 0; t < 32; ++t) {
        const int cur = t & 1;
        asm volatile("s_waitcnt vmcnt(0)" ::: "memory");
        __builtin_amdgcn_s_barrier();
        if (t < 31) STAGE(cur ^ 1, t + 1);

        // ---- QK^T (swapped: A=K rows t, B=Q cols q) ----
        f32x4 s[4];
#pragma unroll
        for (int nf = 0; nf < 4; ++nf) s[nf] = (f32x4){0.f, 0.f, 0.f, 0.f};
#pragma unroll
        for (int nf = 0; nf < 4; ++nf) {
#pragma unroll
            for (int ks = 0; ks < 2; ++ks) {
                int trow = nf * 16 + (lane & 15);
                int koff = trow * 64 + (((ks * 4 + (lane >> 4)) ^ (trow & 7)) * 8);
                bf16x8 kf = *reinterpret_cast<const bf16x8*>(&Kh[cur][koff]);
                s[nf] = __builtin_amdgcn_mfma_f32_16x16x32_bf16(kf, qf[ks], s[nf], 0, 0, 0);
            }
        }

        // ---- p = 2^s ; accumulate l; pack P ----
        int qloc = lane & 15;
#pragma unroll
        for (int nf = 0; nf < 4; ++nf) {
            float p0 = exp2_hw(s[nf][0]);
            float p1 = exp2_hw(s[nf][1]);
            float p2 = exp2_hw(s[nf][2]);
            float p3 = exp2_hw(s[nf][3]);
            l_part += (p0 + p1) + (p2 + p3);
            unsigned w01 = cvt_pk_bf16(p0, p1);
            unsigned w23 = cvt_pk_bf16(p2, p3);
            int tb = nf * 16 + (lane >> 4) * 4;
            int phys = tb ^ ((qloc & 7) << 3);
            *reinterpret_cast<uint2*>(&Ps[w][qloc * 64 + phys]) = make_uint2(w01, w23);
        }

        // ---- PV ----
#pragma unroll
        for (int ks = 0; ks < 2; ++ks) {
            int row = lane & 15;
            int aoff = row * 64 + (((ks * 4 + (lane >> 4)) ^ (row & 7)) * 8);
            bf16x8 pa = *reinterpret_cast<const bf16x8*>(&Ps[w][aoff]);
#pragma unroll
            for (int nf = 0; nf < 4; ++nf) {
                int drow = nf * 16 + (lane & 15);
                int voff = drow * 64 + (((ks * 4 + (lane >> 4)) ^ (drow & 7)) * 8);
                bf16x8 vf = *reinterpret_cast<const bf16x8*>(&Vh[cur][voff]);
                acc[nf] = __builtin_amdgcn_mfma_f32_16x16x32_bf16(pa, vf, acc[nf], 0, 0, 0);
            }
        }
    }
#undef STAGE

    // ---- final l reduce + normalize + store ctx bf16 hi/lo ----
    l_part += __shfl_xor(l_part, 16);
    l_part += __shfl_xor(l_part, 32);
#pragma unroll
    for (int r = 0; r < 4; ++r) {
        float lsum = __shfl(l_part, (lane >> 4) * 4 + r);
        float inv = 1.0f / lsum;
        int qg = q0 + w * 16 + (lane >> 4) * 4 + r;
#pragma unroll
        for (int nf = 0; nf < 4; ++nf) {
            int d = nf * 16 + (lane & 15);
            float val = acc[nf][r] * inv;
            size_t o = ((size_t)(b * SEQ + qg) * NH + h) * KD + d;
            unsigned short hv = f2bf(val);
            ch[o] = hv;
            cl[o] = f2bf(val - bf2f(hv));
        }
    }
}

// ---------------------------------------------------------------------------
extern "C" void kernel_launch(void* const* d_in, const int* in_sizes, int n_in,
                              void* d_out, int out_size, void* d_ws, size_t ws_size,
                              hipStream_t stream) {
    const float* x  = (const float*)d_in[0];
    const float* Wq = (const float*)d_in[1];
    const float* bq = (const float*)d_in[2];
    const float* Wk = (const float*)d_in[3];
    const float* bk = (const float*)d_in[4];
    const float* Wv = (const float*)d_in[5];
    const float* bv = (const float*)d_in[6];
    const float* Wo = (const float*)d_in[7];
    const float* bo = (const float*)d_in[8];
    float* out = (float*)d_out;

    const size_t NE = (size_t)MROWS * DMODEL;   // 4M
    const size_t WE = (size_t)DMODEL * DMODEL;  // 1M
    float* ws    = (float*)d_ws;
    float* sin_t = ws;
    float* cos_t = sin_t + SEQ * 32;
    unsigned short* p = (unsigned short*)(cos_t + SEQ * 32);
    unsigned short* xh   = p; p += NE;
    unsigned short* xl   = p; p += NE;   // ctx_lo (attn writes it)
    unsigned short* qh_  = p; p += NE;
    unsigned short* kh_  = p; p += NE;
    unsigned short* vth  = p; p += NE;
    unsigned short* wth  = p; p += 4 * WE;
    unsigned short* wtl  = p; p += 4 * WE;
    unsigned short* ctxh = xh;
    unsigned short* ctxl = xl;

    k_rope_tables<<<(SEQ * 32 + 255) / 256, 256, 0, stream>>>(sin_t, cos_t);
    k_cvt_x<<<(int)(NE / 4 / 256), 256, 0, stream>>>(x, xh);
    k_cvt_w4<<<dim3(16, 16, 4), 256, 0, stream>>>(Wq, Wk, Wv, Wo, wth, wtl);

    k_mgemm_q<1><<<512, 256, 0, stream>>>(xh, wth + 0 * WE, wtl + 0 * WE, bq, qh_, sin_t, cos_t);
    k_mgemm_q<2><<<512, 256, 0, stream>>>(xh, wth + 1 * WE, wtl + 1 * WE, bk, kh_, sin_t, cos_t);
    k_mgemm_q<3><<<512, 256, 0, stream>>>(xh, wth + 2 * WE, wtl + 2 * WE, bv, vth, nullptr, nullptr);

    k_attn<<<1024, 256, 0, stream>>>(qh_, kh_, vth, ctxh, ctxl);

    k_mgemm_o<<<512, 256, 0, stream>>>(ctxh, ctxl, wth + 3 * WE, wtl + 3 * WE, bo, out);
}

// Round 10
// 158.716 us; speedup vs baseline: 1.1032x; 1.1032x over previous
//
#include <hip/hip_runtime.h>
#include <math.h>

#define NH 16
#define KD 64
#define DMODEL 1024
#define BATCH 2
#define SEQ 2048
#define MROWS (BATCH*SEQ)

typedef float f32x4 __attribute__((ext_vector_type(4)));
typedef __bf16 bf16x8 __attribute__((ext_vector_type(8)));

__device__ __forceinline__ unsigned short f2bf(float x) {
    union { float f; unsigned u; } a; a.f = x;
    unsigned r = a.u + 0x7fffu + ((a.u >> 16) & 1u);
    return (unsigned short)(r >> 16);
}
__device__ __forceinline__ float bf2f(unsigned short h) {
    union { unsigned u; float f; } a; a.u = ((unsigned)h) << 16; return a.f;
}
__device__ __forceinline__ unsigned cvt_pk_bf16(float lo, float hi) {
    unsigned r;
    asm("v_cvt_pk_bf16_f32 %0, %1, %2" : "=v"(r) : "v"(lo), "v"(hi));
    return r;
}
__device__ __forceinline__ float exp2_hw(float x) {
    float r;
    asm("v_exp_f32 %0, %1" : "=v"(r) : "v"(x));
    return r;
}

__device__ __forceinline__ void gl2lds16(const void* gsrc, void* ldst) {
    __builtin_amdgcn_global_load_lds(
        (const __attribute__((address_space(1))) void*)gsrc,
        (__attribute__((address_space(3))) void*)ldst, 16, 0, 0);
}

// ---------------------------------------------------------------------------
__global__ __launch_bounds__(256) void k_rope_tables(float* __restrict__ sin_t,
                                                     float* __restrict__ cos_t) {
    int idx = blockIdx.x * 256 + threadIdx.x;
    if (idx >= SEQ * 32) return;
    int s = idx >> 5, i = idx & 31;
    float invf = expf((float)(2 * i) * (-logf(10000.0f) / (float)KD));
    float ang = (float)s * invf;
    sin_t[idx] = sinf(ang);
    cos_t[idx] = cosf(ang);
}

// ---------------------------------------------------------------------------
__global__ __launch_bounds__(256) void k_cvt_x(const float* __restrict__ x,
                                               unsigned short* __restrict__ xh) {
    int idx = blockIdx.x * 256 + threadIdx.x;
    float4 v = reinterpret_cast<const float4*>(x)[idx];
    ushort4 h;
    h.x = f2bf(v.x); h.y = f2bf(v.y); h.z = f2bf(v.z); h.w = f2bf(v.w);
    reinterpret_cast<ushort4*>(xh)[idx] = h;
}

// ---------------------------------------------------------------------------
__global__ __launch_bounds__(256) void k_cvt_w4(const float* __restrict__ W0,
                                                const float* __restrict__ W1,
                                                const float* __restrict__ W2,
                                                const float* __restrict__ W3,
                                                unsigned short* __restrict__ Th,
                                                unsigned short* __restrict__ Tl) {
    __shared__ float L[64][65];
    const int tid = threadIdx.x;
    const int n0 = blockIdx.x * 64, k0 = blockIdx.y * 64;
    const int z = blockIdx.z;
    const float* W = (z == 0) ? W0 : (z == 1) ? W1 : (z == 2) ? W2 : W3;
    const size_t zoff = (size_t)z * DMODEL * DMODEL;
#pragma unroll
    for (int it = 0; it < 4; ++it) {
        int idx = tid + it * 256;
        int r = idx >> 4;
        int c4 = (idx & 15) * 4;
        float4 v = *reinterpret_cast<const float4*>(&W[(size_t)(k0 + r) * DMODEL + n0 + c4]);
        L[r][c4 + 0] = v.x; L[r][c4 + 1] = v.y; L[r][c4 + 2] = v.z; L[r][c4 + 3] = v.w;
    }
    __syncthreads();
    int rn = tid >> 2;
    int ks = (tid & 3) * 16;
#pragma unroll
    for (int g = 0; g < 4; ++g) {
        ushort4 h, l;
        float v0 = L[ks + g * 4 + 0][rn];
        float v1 = L[ks + g * 4 + 1][rn];
        float v2 = L[ks + g * 4 + 2][rn];
        float v3 = L[ks + g * 4 + 3][rn];
        h.x = f2bf(v0); l.x = f2bf(v0 - bf2f(h.x));
        h.y = f2bf(v1); l.y = f2bf(v1 - bf2f(h.y));
        h.z = f2bf(v2); l.z = f2bf(v2 - bf2f(h.z));
        h.w = f2bf(v3); l.w = f2bf(v3 - bf2f(h.w));
        size_t o = zoff + (size_t)(n0 + rn) * DMODEL + k0 + ks + g * 4;
        *reinterpret_cast<ushort4*>(&Th[o]) = h;
        *reinterpret_cast<ushort4*>(&Tl[o]) = l;
    }
}

// ---------------------------------------------------------------------------
// 2-MFMA split GEMM (ah·bl + ah·bh), single-buffered, 2 barriers/kt,
// 32KB LDS -> 5 blocks/CU. Tile 128x64, BK=64, 4 waves.
// MODE 0: fp32+bias -> Cf (O proj); MODE 1: RoPE*(0.125*log2e) -> bf16 (Q);
// MODE 2: RoPE -> bf16 (K); MODE 3: plain -> bf16 [b,h,d,s] (V^T).
// ---------------------------------------------------------------------------
template<int MODE>
__global__ __launch_bounds__(256) void k_mgemm(const unsigned short* __restrict__ Ah_g,
                                               const unsigned short* __restrict__ Bh_g,
                                               const unsigned short* __restrict__ Bl_g,
                                               const float* __restrict__ bias,
                                               float* __restrict__ Cf,
                                               unsigned short* __restrict__ Ohi,
                                               const float* __restrict__ sin_t,
                                               const float* __restrict__ cos_t) {
    __shared__ unsigned short Ah[128 * 64];
    __shared__ unsigned short Bh[64 * 64];
    __shared__ unsigned short Bl[64 * 64];
    const int tid = threadIdx.x;
    const int lane = tid & 63;
    const int w = tid >> 6;

    int bid = blockIdx.x;
    int wg = (bid & 7) * 64 + (bid >> 3);
    const int m0 = (wg >> 4) * 128;
    const int n0 = (wg & 15) * 64;

    size_t a_goff[4]; int a_ldst[4];
#pragma unroll
    for (int it = 0; it < 4; ++it) {
        int off = it * 4096 + w * 1024 + lane * 16;
        int row = off >> 7;
        int pg = (off >> 4) & 7;
        int lg = pg ^ (row & 7);
        a_goff[it] = (size_t)(m0 + row) * DMODEL + lg * 8;
        a_ldst[it] = it * 2048 + w * 512;
    }
    size_t b_goff[2]; int b_ldst[2];
#pragma unroll
    for (int it = 0; it < 2; ++it) {
        int off = it * 4096 + w * 1024 + lane * 16;
        int row = off >> 7;
        int pg = (off >> 4) & 7;
        int lg = pg ^ (row & 7);
        b_goff[it] = (size_t)(n0 + row) * DMODEL + lg * 8;
        b_ldst[it] = it * 2048 + w * 512;
    }

    int aoff[2][2], boff[4][2];
#pragma unroll
    for (int mf = 0; mf < 2; ++mf)
#pragma unroll
        for (int ks = 0; ks < 2; ++ks) {
            int row = w * 32 + mf * 16 + (lane & 15);
            int g = ks * 4 + (lane >> 4);
            aoff[mf][ks] = row * 64 + ((g ^ (row & 7)) * 8);
        }
#pragma unroll
    for (int nf = 0; nf < 4; ++nf)
#pragma unroll
        for (int ks = 0; ks < 2; ++ks) {
            int row = nf * 16 + (lane & 15);
            int g = ks * 4 + (lane >> 4);
            boff[nf][ks] = row * 64 + ((g ^ (row & 7)) * 8);
        }

    f32x4 acc[2][4];
#pragma unroll
    for (int mf = 0; mf < 2; ++mf)
#pragma unroll
        for (int nf = 0; nf < 4; ++nf) acc[mf][nf] = (f32x4){0.f, 0.f, 0.f, 0.f};

    for (int kt = 0; kt < 16; ++kt) {
        const int k0 = kt * 64;
#pragma unroll
        for (int it = 0; it < 4; ++it)
            gl2lds16(Ah_g + a_goff[it] + k0, &Ah[a_ldst[it]]);
#pragma unroll
        for (int it = 0; it < 2; ++it) {
            gl2lds16(Bh_g + b_goff[it] + k0, &Bh[b_ldst[it]]);
            gl2lds16(Bl_g + b_goff[it] + k0, &Bl[b_ldst[it]]);
        }
        __syncthreads();
#pragma unroll
        for (int ks = 0; ks < 2; ++ks) {
            bf16x8 ah[2], bh[4], bl[4];
#pragma unroll
            for (int mf = 0; mf < 2; ++mf)
                ah[mf] = *reinterpret_cast<const bf16x8*>(&Ah[aoff[mf][ks]]);
#pragma unroll
            for (int nf = 0; nf < 4; ++nf) {
                bh[nf] = *reinterpret_cast<const bf16x8*>(&Bh[boff[nf][ks]]);
                bl[nf] = *reinterpret_cast<const bf16x8*>(&Bl[boff[nf][ks]]);
            }
#pragma unroll
            for (int mf = 0; mf < 2; ++mf)
#pragma unroll
                for (int nf = 0; nf < 4; ++nf) {
                    acc[mf][nf] = __builtin_amdgcn_mfma_f32_16x16x32_bf16(ah[mf], bl[nf], acc[mf][nf], 0, 0, 0);
                    acc[mf][nf] = __builtin_amdgcn_mfma_f32_16x16x32_bf16(ah[mf], bh[nf], acc[mf][nf], 0, 0, 0);
                }
        }
        __syncthreads();
    }

    const int c = lane & 15;
    const int rq = lane >> 4;
    float bv[4];
#pragma unroll
    for (int nf = 0; nf < 4; ++nf) bv[nf] = bias[n0 + nf * 16 + c];

#pragma unroll
    for (int mf = 0; mf < 2; ++mf) {
        int mbase = m0 + w * 32 + mf * 16 + rq * 4;
        if (MODE == 0) {
#pragma unroll
            for (int nf = 0; nf < 4; ++nf)
#pragma unroll
                for (int r = 0; r < 4; ++r)
                    Cf[(size_t)(mbase + r) * DMODEL + n0 + nf * 16 + c] = acc[mf][nf][r] + bv[nf];
        } else if (MODE == 1 || MODE == 2) {
#pragma unroll
            for (int r = 0; r < 4; ++r) {
                int m = mbase + r;
                int srow = m & (SEQ - 1);
                float x0 = acc[mf][0][r] + bv[0];
                float x1 = acc[mf][1][r] + bv[1];
                float x2 = acc[mf][2][r] + bv[2];
                float x3 = acc[mf][3][r] + bv[3];
                float s0 = sin_t[srow * 32 + c],      c0 = cos_t[srow * 32 + c];
                float s1 = sin_t[srow * 32 + 16 + c], c1 = cos_t[srow * 32 + 16 + c];
                float o0 = c0 * x0 - s0 * x2;
                float o2 = s0 * x0 + c0 * x2;
                float o1 = c1 * x1 - s1 * x3;
                float o3 = s1 * x1 + c1 * x3;
                if (MODE == 1) {
                    const float qs = 0.18033688011112042f;   // 0.125*log2(e)
                    o0 *= qs; o1 *= qs; o2 *= qs; o3 *= qs;
                }
                float ov[4] = { o0, o1, o2, o3 };
                size_t base = (size_t)m * DMODEL + n0 + c;
#pragma unroll
                for (int nf = 0; nf < 4; ++nf)
                    Ohi[base + nf * 16] = f2bf(ov[nf]);
            }
        } else {   // MODE 3: V^T [b,h,d,s]
            int bb = mbase >> 11;
            int s = mbase & (SEQ - 1);
            int h = n0 >> 6;
#pragma unroll
            for (int nf = 0; nf < 4; ++nf) {
                ushort4 h4;
                float v0 = acc[mf][nf][0] + bv[nf];
                float v1 = acc[mf][nf][1] + bv[nf];
                float v2 = acc[mf][nf][2] + bv[nf];
                float v3 = acc[mf][nf][3] + bv[nf];
                h4.x = f2bf(v0); h4.y = f2bf(v1); h4.z = f2bf(v2); h4.w = f2bf(v3);
                int d = nf * 16 + c;
                size_t o = ((size_t)((bb * NH + h) * KD + d)) * SEQ + s;
                *reinterpret_cast<ushort4*>(&Ohi[o]) = h4;
            }
        }
    }
}

// ---------------------------------------------------------------------------
// Flash attention: 2 waves/block (128 thr), 64 q-rows/block, wave owns 32
// (mf=2) -> K/V LDS reads amortized 2x. KV tiles 64, dbuf, 1 barrier/tile.
// Unnormalized softmax p=2^s, deferred l-reduce, swapped QK^T.
// LDS 40KB -> 4 blocks/CU. ctx out: bf16 hi only.
// ---------------------------------------------------------------------------
__global__ __launch_bounds__(128) void k_attn(const unsigned short* __restrict__ qhi,
                                              const unsigned short* __restrict__ khi,
                                              const unsigned short* __restrict__ vthi,
                                              unsigned short* __restrict__ ch) {
    __shared__ unsigned short Kh[2][64 * 64];
    __shared__ unsigned short Vh[2][64 * 64];   // [d][t]
    __shared__ unsigned short Ps[2][32 * 64];

    const int tid  = threadIdx.x;
    const int lane = tid & 63;
    const int w    = tid >> 6;                  // 0..1

    int bid = blockIdx.x;
    int wg  = (bid & 7) * 128 + (bid >> 3);     // 1024 blocks, 8 XCD chunks
    const int qt = wg & 31;
    const int h  = (wg >> 5) & 15;
    const int b  = wg >> 9;
    const int q0 = qt * 64;

    // Q fragments (bf16, pre-scaled by 0.125*log2e); wave owns 32 q-rows
    bf16x8 qf[2][2];   // [mf][ks]
#pragma unroll
    for (int mf = 0; mf < 2; ++mf)
#pragma unroll
        for (int ks = 0; ks < 2; ++ks) {
            int row = q0 + w * 32 + mf * 16 + (lane & 15);
            int d = ks * 32 + (lane >> 4) * 8;
            qf[mf][ks] = *reinterpret_cast<const bf16x8*>(
                qhi + ((size_t)(b * SEQ + row) * NH + h) * KD + d);
        }

    // staging: 128 thr x 16B = 2KB/call; K,V tiles 8KB each -> 4+4 calls
    size_t gK[4], gV[4]; int ld_[4];
#pragma unroll
    for (int it = 0; it < 4; ++it) {
        int off = it * 2048 + tid * 16;
        int row = off >> 7;                 // 0..63
        int pg = (off >> 4) & 7;
        int lg = pg ^ (row & 7);
        gK[it] = ((size_t)(b * SEQ + row) * NH + h) * KD + lg * 8;
        gV[it] = ((size_t)(b * NH + h) * KD + row) * SEQ + lg * 8;
        ld_[it] = it * 1024 + w * 512;      // ushort idx, wave-uniform
    }

    f32x4 acc[2][4];
    float l_part[2] = { 0.f, 0.f };
#pragma unroll
    for (int mf = 0; mf < 2; ++mf)
#pragma unroll
        for (int nf = 0; nf < 4; ++nf) acc[mf][nf] = (f32x4){0.f, 0.f, 0.f, 0.f};

#define STAGE(BUF, TT) do {                                                  \
        size_t kadv = (size_t)(TT) * 64 * NH * KD;                           \
        size_t vadv = (size_t)(TT) * 64;                                     \
        gl2lds16(khi  + gK[0] + kadv, &Kh[BUF][ld_[0]]);                     \
        gl2lds16(khi  + gK[1] + kadv, &Kh[BUF][ld_[1]]);                     \
        gl2lds16(khi  + gK[2] + kadv, &Kh[BUF][ld_[2]]);                     \
        gl2lds16(khi  + gK[3] + kadv, &Kh[BUF][ld_[3]]);                     \
        gl2lds16(vthi + gV[0] + vadv, &Vh[BUF][ld_[0]]);                     \
        gl2lds16(vthi + gV[1] + vadv, &Vh[BUF][ld_[1]]);                     \
        gl2lds16(vthi + gV[2] + vadv, &Vh[BUF][ld_[2]]);                     \
        gl2lds16(vthi + gV[3] + vadv, &Vh[BUF][ld_[3]]);                     \
    } while (0)

    STAGE(0, 0);

    for (int t = 0; t < 32; ++t) {
        const int cur = t & 1;
        asm volatile("s_waitcnt vmcnt(0)" ::: "memory");
        __builtin_amdgcn_s_barrier();
        if (t < 31) STAGE(cur ^ 1, t + 1);

        // ---- QK^T (swapped: A=K, shared across mf) ----
        f32x4 s[2][4];
#pragma unroll
        for (int mf = 0; mf < 2; ++mf)
#pragma unroll
            for (int nf = 0; nf < 4; ++nf) s[mf][nf] = (f32x4){0.f, 0.f, 0.f, 0.f};
#pragma unroll
        for (int nf = 0; nf < 4; ++nf) {
#pragma unroll
            for (int ks = 0; ks < 2; ++ks) {
                int trow = nf * 16 + (lane & 15);
                int koff = trow * 64 + (((ks * 4 + (lane >> 4)) ^ (trow & 7)) * 8);
                bf16x8 kf = *reinterpret_cast<const bf16x8*>(&Kh[cur][koff]);
#pragma unroll
                for (int mf = 0; mf < 2; ++mf)
                    s[mf][nf] = __builtin_amdgcn_mfma_f32_16x16x32_bf16(kf, qf[mf][ks], s[mf][nf], 0, 0, 0);
            }
        }

        // ---- p = 2^s ; accumulate l; pack P ----
#pragma unroll
        for (int mf = 0; mf < 2; ++mf) {
            int qloc = mf * 16 + (lane & 15);
#pragma unroll
            for (int nf = 0; nf < 4; ++nf) {
                float p0 = exp2_hw(s[mf][nf][0]);
                float p1 = exp2_hw(s[mf][nf][1]);
                float p2 = exp2_hw(s[mf][nf][2]);
                float p3 = exp2_hw(s[mf][nf][3]);
                l_part[mf] += (p0 + p1) + (p2 + p3);
                unsigned w01 = cvt_pk_bf16(p0, p1);
                unsigned w23 = cvt_pk_bf16(p2, p3);
                int tb = nf * 16 + (lane >> 4) * 4;
                int phys = tb ^ ((qloc & 7) << 3);
                *reinterpret_cast<uint2*>(&Ps[w][qloc * 64 + phys]) = make_uint2(w01, w23);
            }
        }

        // ---- PV (V reads shared across mf) ----
#pragma unroll
        for (int ks = 0; ks < 2; ++ks) {
            bf16x8 pa[2];
#pragma unroll
            for (int mf = 0; mf < 2; ++mf) {
                int row = mf * 16 + (lane & 15);
                int aoff = row * 64 + (((ks * 4 + (lane >> 4)) ^ (row & 7)) * 8);
                pa[mf] = *reinterpret_cast<const bf16x8*>(&Ps[w][aoff]);
            }
#pragma unroll
            for (int nf = 0; nf < 4; ++nf) {
                int drow = nf * 16 + (lane & 15);
                int voff = drow * 64 + (((ks * 4 + (lane >> 4)) ^ (drow & 7)) * 8);
                bf16x8 vf = *reinterpret_cast<const bf16x8*>(&Vh[cur][voff]);
#pragma unroll
                for (int mf = 0; mf < 2; ++mf)
                    acc[mf][nf] = __builtin_amdgcn_mfma_f32_16x16x32_bf16(pa[mf], vf, acc[mf][nf], 0, 0, 0);
            }
        }
    }
#undef STAGE

    // ---- final l reduce + normalize + store ctx bf16 hi ----
#pragma unroll
    for (int mf = 0; mf < 2; ++mf) {
        l_part[mf] += __shfl_xor(l_part[mf], 16);
        l_part[mf] += __shfl_xor(l_part[mf], 32);
    }
#pragma unroll
    for (int mf = 0; mf < 2; ++mf) {
#pragma unroll
        for (int r = 0; r < 4; ++r) {
            float lsum = __shfl(l_part[mf], (lane >> 4) * 4 + r);
            float inv = 1.0f / lsum;
            int qg = q0 + w * 32 + mf * 16 + (lane >> 4) * 4 + r;
#pragma unroll
            for (int nf = 0; nf < 4; ++nf) {
                int d = nf * 16 + (lane & 15);
                float val = acc[mf][nf][r] * inv;
                ch[((size_t)(b * SEQ + qg) * NH + h) * KD + d] = f2bf(val);
            }
        }
    }
}

// ---------------------------------------------------------------------------
extern "C" void kernel_launch(void* const* d_in, const int* in_sizes, int n_in,
                              void* d_out, int out_size, void* d_ws, size_t ws_size,
                              hipStream_t stream) {
    const float* x  = (const float*)d_in[0];
    const float* Wq = (const float*)d_in[1];
    const float* bq = (const float*)d_in[2];
    const float* Wk = (const float*)d_in[3];
    const float* bk = (const float*)d_in[4];
    const float* Wv = (const float*)d_in[5];
    const float* bv = (const float*)d_in[6];
    const float* Wo = (const float*)d_in[7];
    const float* bo = (const float*)d_in[8];
    float* out = (float*)d_out;

    const size_t NE = (size_t)MROWS * DMODEL;   // 4M
    const size_t WE = (size_t)DMODEL * DMODEL;  // 1M
    float* ws    = (float*)d_ws;
    float* sin_t = ws;
    float* cos_t = sin_t + SEQ * 32;
    unsigned short* p = (unsigned short*)(cos_t + SEQ * 32);
    unsigned short* xh   = p; p += NE;
    unsigned short* qh_  = p; p += NE;
    unsigned short* kh_  = p; p += NE;
    unsigned short* vth  = p; p += NE;
    unsigned short* wth  = p; p += 4 * WE;
    unsigned short* wtl  = p; p += 4 * WE;
    unsigned short* ctxh = xh;   // alias: x dead after V projection

    k_rope_tables<<<(SEQ * 32 + 255) / 256, 256, 0, stream>>>(sin_t, cos_t);
    k_cvt_x<<<(int)(NE / 4 / 256), 256, 0, stream>>>(x, xh);
    k_cvt_w4<<<dim3(16, 16, 4), 256, 0, stream>>>(Wq, Wk, Wv, Wo, wth, wtl);

    k_mgemm<1><<<512, 256, 0, stream>>>(xh, wth + 0 * WE, wtl + 0 * WE, bq, nullptr, qh_, sin_t, cos_t);
    k_mgemm<2><<<512, 256, 0, stream>>>(xh, wth + 1 * WE, wtl + 1 * WE, bk, nullptr, kh_, sin_t, cos_t);
    k_mgemm<3><<<512, 256, 0, stream>>>(xh, wth + 2 * WE, wtl + 2 * WE, bv, nullptr, vth, nullptr, nullptr);

    k_attn<<<1024, 128, 0, stream>>>(qh_, kh_, vth, ctxh);

    k_mgemm<0><<<512, 256, 0, stream>>>(ctxh, wth + 3 * WE, wtl + 3 * WE, bo, out, nullptr, nullptr, nullptr);
}

// Round 11
// 153.712 us; speedup vs baseline: 1.1392x; 1.0326x over previous
//
#include <hip/hip_runtime.h>
#include <math.h>

#define NH 16
#define KD 64
#define DMODEL 1024
#define BATCH 2
#define SEQ 2048
#define MROWS (BATCH*SEQ)

typedef float f32x4 __attribute__((ext_vector_type(4)));
typedef __bf16 bf16x8 __attribute__((ext_vector_type(8)));

__device__ __forceinline__ unsigned short f2bf(float x) {
    union { float f; unsigned u; } a; a.f = x;
    unsigned r = a.u + 0x7fffu + ((a.u >> 16) & 1u);
    return (unsigned short)(r >> 16);
}
__device__ __forceinline__ float bf2f(unsigned short h) {
    union { unsigned u; float f; } a; a.u = ((unsigned)h) << 16; return a.f;
}
__device__ __forceinline__ unsigned cvt_pk_bf16(float lo, float hi) {
    unsigned r;
    asm("v_cvt_pk_bf16_f32 %0, %1, %2" : "=v"(r) : "v"(lo), "v"(hi));
    return r;
}
__device__ __forceinline__ float exp2_hw(float x) {
    float r;
    asm("v_exp_f32 %0, %1" : "=v"(r) : "v"(x));
    return r;
}

__device__ __forceinline__ void gl2lds16(const void* gsrc, void* ldst) {
    __builtin_amdgcn_global_load_lds(
        (const __attribute__((address_space(1))) void*)gsrc,
        (__attribute__((address_space(3))) void*)ldst, 16, 0, 0);
}

// ---------------------------------------------------------------------------
__global__ __launch_bounds__(256) void k_rope_tables(float* __restrict__ sin_t,
                                                     float* __restrict__ cos_t) {
    int idx = blockIdx.x * 256 + threadIdx.x;
    if (idx >= SEQ * 32) return;
    int s = idx >> 5, i = idx & 31;
    float invf = expf((float)(2 * i) * (-logf(10000.0f) / (float)KD));
    float ang = (float)s * invf;
    sin_t[idx] = sinf(ang);
    cos_t[idx] = cosf(ang);
}

// ---------------------------------------------------------------------------
__global__ __launch_bounds__(256) void k_cvt_x(const float* __restrict__ x,
                                               unsigned short* __restrict__ xh) {
    int idx = blockIdx.x * 256 + threadIdx.x;
    float4 v = reinterpret_cast<const float4*>(x)[idx];
    ushort4 h;
    h.x = f2bf(v.x); h.y = f2bf(v.y); h.z = f2bf(v.z); h.w = f2bf(v.w);
    reinterpret_cast<ushort4*>(xh)[idx] = h;
}

// ---------------------------------------------------------------------------
__global__ __launch_bounds__(256) void k_cvt_w4(const float* __restrict__ W0,
                                                const float* __restrict__ W1,
                                                const float* __restrict__ W2,
                                                const float* __restrict__ W3,
                                                unsigned short* __restrict__ Th,
                                                unsigned short* __restrict__ Tl) {
    __shared__ float L[64][65];
    const int tid = threadIdx.x;
    const int n0 = blockIdx.x * 64, k0 = blockIdx.y * 64;
    const int z = blockIdx.z;
    const float* W = (z == 0) ? W0 : (z == 1) ? W1 : (z == 2) ? W2 : W3;
    const size_t zoff = (size_t)z * DMODEL * DMODEL;
#pragma unroll
    for (int it = 0; it < 4; ++it) {
        int idx = tid + it * 256;
        int r = idx >> 4;
        int c4 = (idx & 15) * 4;
        float4 v = *reinterpret_cast<const float4*>(&W[(size_t)(k0 + r) * DMODEL + n0 + c4]);
        L[r][c4 + 0] = v.x; L[r][c4 + 1] = v.y; L[r][c4 + 2] = v.z; L[r][c4 + 3] = v.w;
    }
    __syncthreads();
    int rn = tid >> 2;
    int ks = (tid & 3) * 16;
#pragma unroll
    for (int g = 0; g < 4; ++g) {
        ushort4 h, l;
        float v0 = L[ks + g * 4 + 0][rn];
        float v1 = L[ks + g * 4 + 1][rn];
        float v2 = L[ks + g * 4 + 2][rn];
        float v3 = L[ks + g * 4 + 3][rn];
        h.x = f2bf(v0); l.x = f2bf(v0 - bf2f(h.x));
        h.y = f2bf(v1); l.y = f2bf(v1 - bf2f(h.y));
        h.z = f2bf(v2); l.z = f2bf(v2 - bf2f(h.z));
        h.w = f2bf(v3); l.w = f2bf(v3 - bf2f(h.w));
        size_t o = zoff + (size_t)(n0 + rn) * DMODEL + k0 + ks + g * 4;
        *reinterpret_cast<ushort4*>(&Th[o]) = h;
        *reinterpret_cast<ushort4*>(&Tl[o]) = l;
    }
}

// ---------------------------------------------------------------------------
// 2-MFMA split GEMM (ah·bl + ah·bh), single-buffered, 2 barriers/kt,
// 32KB LDS -> 5 blocks/CU. Tile 128x64, BK=64, 4 waves.
// MODE 0: fp32+bias -> Cf (O proj); MODE 1: RoPE*(0.125*log2e) -> bf16 (Q);
// MODE 2: RoPE -> bf16 (K); MODE 3: plain -> bf16 [b,h,d,s] (V^T).
// ---------------------------------------------------------------------------
template<int MODE>
__global__ __launch_bounds__(256) void k_mgemm(const unsigned short* __restrict__ Ah_g,
                                               const unsigned short* __restrict__ Bh_g,
                                               const unsigned short* __restrict__ Bl_g,
                                               const float* __restrict__ bias,
                                               float* __restrict__ Cf,
                                               unsigned short* __restrict__ Ohi,
                                               const float* __restrict__ sin_t,
                                               const float* __restrict__ cos_t) {
    __shared__ unsigned short Ah[128 * 64];
    __shared__ unsigned short Bh[64 * 64];
    __shared__ unsigned short Bl[64 * 64];
    const int tid = threadIdx.x;
    const int lane = tid & 63;
    const int w = tid >> 6;

    int bid = blockIdx.x;
    int wg = (bid & 7) * 64 + (bid >> 3);
    const int m0 = (wg >> 4) * 128;
    const int n0 = (wg & 15) * 64;

    size_t a_goff[4]; int a_ldst[4];
#pragma unroll
    for (int it = 0; it < 4; ++it) {
        int off = it * 4096 + w * 1024 + lane * 16;
        int row = off >> 7;
        int pg = (off >> 4) & 7;
        int lg = pg ^ (row & 7);
        a_goff[it] = (size_t)(m0 + row) * DMODEL + lg * 8;
        a_ldst[it] = it * 2048 + w * 512;
    }
    size_t b_goff[2]; int b_ldst[2];
#pragma unroll
    for (int it = 0; it < 2; ++it) {
        int off = it * 4096 + w * 1024 + lane * 16;
        int row = off >> 7;
        int pg = (off >> 4) & 7;
        int lg = pg ^ (row & 7);
        b_goff[it] = (size_t)(n0 + row) * DMODEL + lg * 8;
        b_ldst[it] = it * 2048 + w * 512;
    }

    int aoff[2][2], boff[4][2];
#pragma unroll
    for (int mf = 0; mf < 2; ++mf)
#pragma unroll
        for (int ks = 0; ks < 2; ++ks) {
            int row = w * 32 + mf * 16 + (lane & 15);
            int g = ks * 4 + (lane >> 4);
            aoff[mf][ks] = row * 64 + ((g ^ (row & 7)) * 8);
        }
#pragma unroll
    for (int nf = 0; nf < 4; ++nf)
#pragma unroll
        for (int ks = 0; ks < 2; ++ks) {
            int row = nf * 16 + (lane & 15);
            int g = ks * 4 + (lane >> 4);
            boff[nf][ks] = row * 64 + ((g ^ (row & 7)) * 8);
        }

    f32x4 acc[2][4];
#pragma unroll
    for (int mf = 0; mf < 2; ++mf)
#pragma unroll
        for (int nf = 0; nf < 4; ++nf) acc[mf][nf] = (f32x4){0.f, 0.f, 0.f, 0.f};

    for (int kt = 0; kt < 16; ++kt) {
        const int k0 = kt * 64;
#pragma unroll
        for (int it = 0; it < 4; ++it)
            gl2lds16(Ah_g + a_goff[it] + k0, &Ah[a_ldst[it]]);
#pragma unroll
        for (int it = 0; it < 2; ++it) {
            gl2lds16(Bh_g + b_goff[it] + k0, &Bh[b_ldst[it]]);
            gl2lds16(Bl_g + b_goff[it] + k0, &Bl[b_ldst[it]]);
        }
        __syncthreads();
#pragma unroll
        for (int ks = 0; ks < 2; ++ks) {
            bf16x8 ah[2], bh[4], bl[4];
#pragma unroll
            for (int mf = 0; mf < 2; ++mf)
                ah[mf] = *reinterpret_cast<const bf16x8*>(&Ah[aoff[mf][ks]]);
#pragma unroll
            for (int nf = 0; nf < 4; ++nf) {
                bh[nf] = *reinterpret_cast<const bf16x8*>(&Bh[boff[nf][ks]]);
                bl[nf] = *reinterpret_cast<const bf16x8*>(&Bl[boff[nf][ks]]);
            }
#pragma unroll
            for (int mf = 0; mf < 2; ++mf)
#pragma unroll
                for (int nf = 0; nf < 4; ++nf) {
                    acc[mf][nf] = __builtin_amdgcn_mfma_f32_16x16x32_bf16(ah[mf], bl[nf], acc[mf][nf], 0, 0, 0);
                    acc[mf][nf] = __builtin_amdgcn_mfma_f32_16x16x32_bf16(ah[mf], bh[nf], acc[mf][nf], 0, 0, 0);
                }
        }
        __syncthreads();
    }

    const int c = lane & 15;
    const int rq = lane >> 4;
    float bv[4];
#pragma unroll
    for (int nf = 0; nf < 4; ++nf) bv[nf] = bias[n0 + nf * 16 + c];

#pragma unroll
    for (int mf = 0; mf < 2; ++mf) {
        int mbase = m0 + w * 32 + mf * 16 + rq * 4;
        if (MODE == 0) {
#pragma unroll
            for (int nf = 0; nf < 4; ++nf)
#pragma unroll
                for (int r = 0; r < 4; ++r)
                    Cf[(size_t)(mbase + r) * DMODEL + n0 + nf * 16 + c] = acc[mf][nf][r] + bv[nf];
        } else if (MODE == 1 || MODE == 2) {
#pragma unroll
            for (int r = 0; r < 4; ++r) {
                int m = mbase + r;
                int srow = m & (SEQ - 1);
                float x0 = acc[mf][0][r] + bv[0];
                float x1 = acc[mf][1][r] + bv[1];
                float x2 = acc[mf][2][r] + bv[2];
                float x3 = acc[mf][3][r] + bv[3];
                float s0 = sin_t[srow * 32 + c],      c0 = cos_t[srow * 32 + c];
                float s1 = sin_t[srow * 32 + 16 + c], c1 = cos_t[srow * 32 + 16 + c];
                float o0 = c0 * x0 - s0 * x2;
                float o2 = s0 * x0 + c0 * x2;
                float o1 = c1 * x1 - s1 * x3;
                float o3 = s1 * x1 + c1 * x3;
                if (MODE == 1) {
                    const float qs = 0.18033688011112042f;   // 0.125*log2(e)
                    o0 *= qs; o1 *= qs; o2 *= qs; o3 *= qs;
                }
                float ov[4] = { o0, o1, o2, o3 };
                size_t base = (size_t)m * DMODEL + n0 + c;
#pragma unroll
                for (int nf = 0; nf < 4; ++nf)
                    Ohi[base + nf * 16] = f2bf(ov[nf]);
            }
        } else {   // MODE 3: V^T [b,h,d,s]
            int bb = mbase >> 11;
            int s = mbase & (SEQ - 1);
            int h = n0 >> 6;
#pragma unroll
            for (int nf = 0; nf < 4; ++nf) {
                ushort4 h4;
                float v0 = acc[mf][nf][0] + bv[nf];
                float v1 = acc[mf][nf][1] + bv[nf];
                float v2 = acc[mf][nf][2] + bv[nf];
                float v3 = acc[mf][nf][3] + bv[nf];
                h4.x = f2bf(v0); h4.y = f2bf(v1); h4.z = f2bf(v2); h4.w = f2bf(v3);
                int d = nf * 16 + c;
                size_t o = ((size_t)((bb * NH + h) * KD + d)) * SEQ + s;
                *reinterpret_cast<ushort4*>(&Ohi[o]) = h4;
            }
        }
    }
}

// ---------------------------------------------------------------------------
// Flash attention, deferred-PV pipeline: per tile, ONE barrier; stage(t+1)
// issued right after; QK(t) and PV(t-1) MFMAs back-to-back (setprio-wrapped);
// exp(t)/pack(t) in the barrier-free tail. V 3-buffer ring resolves the
// stage-vs-deferred-PV WAR hazard; K 2-buffer; Ps wave-private.
// 4 waves, 128 q-rows/block (wave owns 32, mf=2), 512 blocks = 2/CU.
// Unnormalized softmax p=2^s, deferred l-reduce, swapped QK^T.
// ---------------------------------------------------------------------------
__global__ __launch_bounds__(256) void k_attn(const unsigned short* __restrict__ qhi,
                                              const unsigned short* __restrict__ khi,
                                              const unsigned short* __restrict__ vthi,
                                              unsigned short* __restrict__ ch) {
    __shared__ unsigned short Kh[2][64 * 64];
    __shared__ unsigned short Vh[3][64 * 64];   // [d][t], ring
    __shared__ unsigned short Ps[4][32 * 64];

    const int tid  = threadIdx.x;
    const int lane = tid & 63;
    const int w    = tid >> 6;                  // 0..3

    int bid = blockIdx.x;
    int wg  = (bid & 7) * 64 + (bid >> 3);      // 512 blocks, 8 XCD chunks
    const int qt = wg & 15;
    const int h  = (wg >> 4) & 15;
    const int b  = wg >> 8;
    const int q0 = qt * 128;

    // Q fragments (bf16, pre-scaled by 0.125*log2e); wave owns 32 q-rows
    bf16x8 qf[2][2];   // [mf][ks]
#pragma unroll
    for (int mf = 0; mf < 2; ++mf)
#pragma unroll
        for (int ks = 0; ks < 2; ++ks) {
            int row = q0 + w * 32 + mf * 16 + (lane & 15);
            int d = ks * 32 + (lane >> 4) * 8;
            qf[mf][ks] = *reinterpret_cast<const bf16x8*>(
                qhi + ((size_t)(b * SEQ + row) * NH + h) * KD + d);
        }

    // staging: 256 thr x 16B = 4KB/call; K,V tiles 8KB -> 2 calls each
    size_t gK[2], gV[2]; int ld_[2];
#pragma unroll
    for (int it = 0; it < 2; ++it) {
        int off = it * 4096 + tid * 16;
        int row = off >> 7;                 // 0..63
        int pg = (off >> 4) & 7;
        int lg = pg ^ (row & 7);
        gK[it] = ((size_t)(b * SEQ + row) * NH + h) * KD + lg * 8;
        gV[it] = ((size_t)(b * NH + h) * KD + row) * SEQ + lg * 8;
        ld_[it] = it * 2048 + w * 512;      // ushort idx, wave-uniform
    }

    f32x4 acc[2][4];
    float l_part[2] = { 0.f, 0.f };
#pragma unroll
    for (int mf = 0; mf < 2; ++mf)
#pragma unroll
        for (int nf = 0; nf < 4; ++nf) acc[mf][nf] = (f32x4){0.f, 0.f, 0.f, 0.f};

#define STAGE(KB, VB, TT) do {                                               \
        size_t kadv = (size_t)(TT) * 64 * NH * KD;                           \
        size_t vadv = (size_t)(TT) * 64;                                     \
        gl2lds16(khi  + gK[0] + kadv, &Kh[KB][ld_[0]]);                      \
        gl2lds16(khi  + gK[1] + kadv, &Kh[KB][ld_[1]]);                      \
        gl2lds16(vthi + gV[0] + vadv, &Vh[VB][ld_[0]]);                      \
        gl2lds16(vthi + gV[1] + vadv, &Vh[VB][ld_[1]]);                      \
    } while (0)

#define PV_STEP(VSRC) do {                                                   \
        _Pragma("unroll")                                                    \
        for (int ks = 0; ks < 2; ++ks) {                                     \
            bf16x8 pa[2];                                                    \
            _Pragma("unroll")                                                \
            for (int mf = 0; mf < 2; ++mf) {                                 \
                int prow = mf * 16 + (lane & 15);                            \
                int aoff = prow * 64 + (((ks * 4 + (lane >> 4)) ^ (prow & 7)) * 8); \
                pa[mf] = *reinterpret_cast<const bf16x8*>(&Ps[w][aoff]);     \
            }                                                                \
            _Pragma("unroll")                                                \
            for (int nf = 0; nf < 4; ++nf) {                                 \
                int drow = nf * 16 + (lane & 15);                            \
                int voff = drow * 64 + (((ks * 4 + (lane >> 4)) ^ (drow & 7)) * 8); \
                bf16x8 vf = *reinterpret_cast<const bf16x8*>(&Vh[VSRC][voff]); \
                _Pragma("unroll")                                            \
                for (int mf = 0; mf < 2; ++mf)                               \
                    acc[mf][nf] = __builtin_amdgcn_mfma_f32_16x16x32_bf16(pa[mf], vf, acc[mf][nf], 0, 0, 0); \
            }                                                                \
        }                                                                    \
    } while (0)

    STAGE(0, 0, 0);

    int vnext = 1;   // (t+1)%3 stage target
    int vprev = 2;   // (t-1)%3 PV source (valid from t=1)

    for (int t = 0; t < 32; ++t) {
        const int ck = t & 1;
        asm volatile("s_waitcnt vmcnt(0)" ::: "memory");
        __builtin_amdgcn_s_barrier();
        if (t < 31) STAGE(ck ^ 1, vnext, t + 1);

        __builtin_amdgcn_s_setprio(1);
        // ---- QK^T(t) (swapped: A=K, shared across mf) ----
        f32x4 s[2][4];
#pragma unroll
        for (int mf = 0; mf < 2; ++mf)
#pragma unroll
            for (int nf = 0; nf < 4; ++nf) s[mf][nf] = (f32x4){0.f, 0.f, 0.f, 0.f};
#pragma unroll
        for (int nf = 0; nf < 4; ++nf) {
#pragma unroll
            for (int ks = 0; ks < 2; ++ks) {
                int trow = nf * 16 + (lane & 15);
                int koff = trow * 64 + (((ks * 4 + (lane >> 4)) ^ (trow & 7)) * 8);
                bf16x8 kf = *reinterpret_cast<const bf16x8*>(&Kh[ck][koff]);
#pragma unroll
                for (int mf = 0; mf < 2; ++mf)
                    s[mf][nf] = __builtin_amdgcn_mfma_f32_16x16x32_bf16(kf, qf[mf][ks], s[mf][nf], 0, 0, 0);
            }
        }
        // ---- PV(t-1): independent MFMAs, fills matrix pipe while exp waits ----
        if (t > 0) PV_STEP(vprev);
        __builtin_amdgcn_s_setprio(0);

        // ---- exp(t) + pack -> Ps (barrier-free tail; overlaps other waves' MFMA) ----
#pragma unroll
        for (int mf = 0; mf < 2; ++mf) {
            int qloc = mf * 16 + (lane & 15);
#pragma unroll
            for (int nf = 0; nf < 4; ++nf) {
                float p0 = exp2_hw(s[mf][nf][0]);
                float p1 = exp2_hw(s[mf][nf][1]);
                float p2 = exp2_hw(s[mf][nf][2]);
                float p3 = exp2_hw(s[mf][nf][3]);
                l_part[mf] += (p0 + p1) + (p2 + p3);
                unsigned w01 = cvt_pk_bf16(p0, p1);
                unsigned w23 = cvt_pk_bf16(p2, p3);
                int tb = nf * 16 + (lane >> 4) * 4;
                int phys = tb ^ ((qloc & 7) << 3);
                *reinterpret_cast<uint2*>(&Ps[w][qloc * 64 + phys]) = make_uint2(w01, w23);
            }
        }

        vnext = (vnext == 2) ? 0 : vnext + 1;
        vprev = (vprev == 2) ? 0 : vprev + 1;
    }

    // ---- epilogue: PV(31) ----
    PV_STEP(vprev);
#undef PV_STEP
#undef STAGE

    // ---- final l reduce + normalize + store ctx bf16 hi ----
#pragma unroll
    for (int mf = 0; mf < 2; ++mf) {
        l_part[mf] += __shfl_xor(l_part[mf], 16);
        l_part[mf] += __shfl_xor(l_part[mf], 32);
    }
#pragma unroll
    for (int mf = 0; mf < 2; ++mf) {
#pragma unroll
        for (int r = 0; r < 4; ++r) {
            float lsum = __shfl(l_part[mf], (lane >> 4) * 4 + r);
            float inv = 1.0f / lsum;
            int qg = q0 + w * 32 + mf * 16 + (lane >> 4) * 4 + r;
#pragma unroll
            for (int nf = 0; nf < 4; ++nf) {
                int d = nf * 16 + (lane & 15);
                float val = acc[mf][nf][r] * inv;
                ch[((size_t)(b * SEQ + qg) * NH + h) * KD + d] = f2bf(val);
            }
        }
    }
}

// ---------------------------------------------------------------------------
extern "C" void kernel_launch(void* const* d_in, const int* in_sizes, int n_in,
                              void* d_out, int out_size, void* d_ws, size_t ws_size,
                              hipStream_t stream) {
    const float* x  = (const float*)d_in[0];
    const float* Wq = (const float*)d_in[1];
    const float* bq = (const float*)d_in[2];
    const float* Wk = (const float*)d_in[3];
    const float* bk = (const float*)d_in[4];
    const float* Wv = (const float*)d_in[5];
    const float* bv = (const float*)d_in[6];
    const float* Wo = (const float*)d_in[7];
    const float* bo = (const float*)d_in[8];
    float* out = (float*)d_out;

    const size_t NE = (size_t)MROWS * DMODEL;   // 4M
    const size_t WE = (size_t)DMODEL * DMODEL;  // 1M
    float* ws    = (float*)d_ws;
    float* sin_t = ws;
    float* cos_t = sin_t + SEQ * 32;
    unsigned short* p = (unsigned short*)(cos_t + SEQ * 32);
    unsigned short* xh   = p; p += NE;
    unsigned short* qh_  = p; p += NE;
    unsigned short* kh_  = p; p += NE;
    unsigned short* vth  = p; p += NE;
    unsigned short* wth  = p; p += 4 * WE;
    unsigned short* wtl  = p; p += 4 * WE;
    unsigned short* ctxh = xh;   // alias: x dead after V projection

    k_rope_tables<<<(SEQ * 32 + 255) / 256, 256, 0, stream>>>(sin_t, cos_t);
    k_cvt_x<<<(int)(NE / 4 / 256), 256, 0, stream>>>(x, xh);
    k_cvt_w4<<<dim3(16, 16, 4), 256, 0, stream>>>(Wq, Wk, Wv, Wo, wth, wtl);

    k_mgemm<1><<<512, 256, 0, stream>>>(xh, wth + 0 * WE, wtl + 0 * WE, bq, nullptr, qh_, sin_t, cos_t);
    k_mgemm<2><<<512, 256, 0, stream>>>(xh, wth + 1 * WE, wtl + 1 * WE, bk, nullptr, kh_, sin_t, cos_t);
    k_mgemm<3><<<512, 256, 0, stream>>>(xh, wth + 2 * WE, wtl + 2 * WE, bv, nullptr, vth, nullptr, nullptr);

    k_attn<<<512, 256, 0, stream>>>(qh_, kh_, vth, ctxh);

    k_mgemm<0><<<512, 256, 0, stream>>>(ctxh, wth + 3 * WE, wtl + 3 * WE, bo, out, nullptr, nullptr, nullptr);
}

// Round 12
// 137.858 us; speedup vs baseline: 1.2702x; 1.1150x over previous
//
#include <hip/hip_runtime.h>
#include <math.h>

#define NH 16
#define KD 64
#define DMODEL 1024
#define BATCH 2
#define SEQ 2048
#define MROWS (BATCH*SEQ)

typedef float f32x4 __attribute__((ext_vector_type(4)));
typedef __bf16 bf16x8 __attribute__((ext_vector_type(8)));

__device__ __forceinline__ unsigned short f2bf(float x) {
    union { float f; unsigned u; } a; a.f = x;
    unsigned r = a.u + 0x7fffu + ((a.u >> 16) & 1u);
    return (unsigned short)(r >> 16);
}
__device__ __forceinline__ float bf2f(unsigned short h) {
    union { unsigned u; float f; } a; a.u = ((unsigned)h) << 16; return a.f;
}
__device__ __forceinline__ unsigned cvt_pk_bf16(float lo, float hi) {
    unsigned r;
    asm("v_cvt_pk_bf16_f32 %0, %1, %2" : "=v"(r) : "v"(lo), "v"(hi));
    return r;
}
__device__ __forceinline__ float exp2_hw(float x) {
    float r;
    asm("v_exp_f32 %0, %1" : "=v"(r) : "v"(x));
    return r;
}

__device__ __forceinline__ void gl2lds16(const void* gsrc, void* ldst) {
    __builtin_amdgcn_global_load_lds(
        (const __attribute__((address_space(1))) void*)gsrc,
        (__attribute__((address_space(3))) void*)ldst, 16, 0, 0);
}

// ---------------------------------------------------------------------------
__global__ __launch_bounds__(256) void k_rope_tables(float* __restrict__ sin_t,
                                                     float* __restrict__ cos_t) {
    int idx = blockIdx.x * 256 + threadIdx.x;
    if (idx >= SEQ * 32) return;
    int s = idx >> 5, i = idx & 31;
    float invf = expf((float)(2 * i) * (-logf(10000.0f) / (float)KD));
    float ang = (float)s * invf;
    sin_t[idx] = sinf(ang);
    cos_t[idx] = cosf(ang);
}

// ---------------------------------------------------------------------------
__global__ __launch_bounds__(256) void k_cvt_x(const float* __restrict__ x,
                                               unsigned short* __restrict__ xh) {
    int idx = blockIdx.x * 256 + threadIdx.x;
    float4 v = reinterpret_cast<const float4*>(x)[idx];
    ushort4 h;
    h.x = f2bf(v.x); h.y = f2bf(v.y); h.z = f2bf(v.z); h.w = f2bf(v.w);
    reinterpret_cast<ushort4*>(xh)[idx] = h;
}

// ---------------------------------------------------------------------------
// 4 weights [k][n] fp32 -> Wt [n][k] bf16 hi (z = which weight)
// ---------------------------------------------------------------------------
__global__ __launch_bounds__(256) void k_cvt_w4(const float* __restrict__ W0,
                                                const float* __restrict__ W1,
                                                const float* __restrict__ W2,
                                                const float* __restrict__ W3,
                                                unsigned short* __restrict__ Th) {
    __shared__ float L[64][65];
    const int tid = threadIdx.x;
    const int n0 = blockIdx.x * 64, k0 = blockIdx.y * 64;
    const int z = blockIdx.z;
    const float* W = (z == 0) ? W0 : (z == 1) ? W1 : (z == 2) ? W2 : W3;
    const size_t zoff = (size_t)z * DMODEL * DMODEL;
#pragma unroll
    for (int it = 0; it < 4; ++it) {
        int idx = tid + it * 256;
        int r = idx >> 4;
        int c4 = (idx & 15) * 4;
        float4 v = *reinterpret_cast<const float4*>(&W[(size_t)(k0 + r) * DMODEL + n0 + c4]);
        L[r][c4 + 0] = v.x; L[r][c4 + 1] = v.y; L[r][c4 + 2] = v.z; L[r][c4 + 3] = v.w;
    }
    __syncthreads();
    int rn = tid >> 2;
    int ks = (tid & 3) * 16;
#pragma unroll
    for (int g = 0; g < 4; ++g) {
        ushort4 h;
        h.x = f2bf(L[ks + g * 4 + 0][rn]);
        h.y = f2bf(L[ks + g * 4 + 1][rn]);
        h.z = f2bf(L[ks + g * 4 + 2][rn]);
        h.w = f2bf(L[ks + g * 4 + 3][rn]);
        size_t o = zoff + (size_t)(n0 + rn) * DMODEL + k0 + ks + g * 4;
        *reinterpret_cast<ushort4*>(&Th[o]) = h;
    }
}

// ---------------------------------------------------------------------------
// Plain-bf16 MFMA GEMM, double-buffered, 1 barrier/kt. Tile 128x64, BK=64,
// 4 waves. LDS 48KB; grid 512 = 2 blocks/CU (grid-capped, dbuf free).
// MODE 0: fp32+bias -> Cf (O proj); MODE 1: RoPE*(0.125*log2e) -> bf16 (Q);
// MODE 2: RoPE -> bf16 (K); MODE 3: plain -> bf16 [b,h,d,s] (V^T).
// ---------------------------------------------------------------------------
template<int MODE>
__global__ __launch_bounds__(256) void k_mgemm(const unsigned short* __restrict__ Ah_g,
                                               const unsigned short* __restrict__ Bh_g,
                                               const float* __restrict__ bias,
                                               float* __restrict__ Cf,
                                               unsigned short* __restrict__ Ohi,
                                               const float* __restrict__ sin_t,
                                               const float* __restrict__ cos_t) {
    __shared__ unsigned short Ah[2][128 * 64];
    __shared__ unsigned short Bh[2][64 * 64];
    const int tid = threadIdx.x;
    const int lane = tid & 63;
    const int w = tid >> 6;

    int bid = blockIdx.x;
    int wg = (bid & 7) * 64 + (bid >> 3);
    const int m0 = (wg >> 4) * 128;
    const int n0 = (wg & 15) * 64;

    size_t a_goff[4]; int a_ldst[4];
#pragma unroll
    for (int it = 0; it < 4; ++it) {
        int off = it * 4096 + w * 1024 + lane * 16;
        int row = off >> 7;
        int pg = (off >> 4) & 7;
        int lg = pg ^ (row & 7);
        a_goff[it] = (size_t)(m0 + row) * DMODEL + lg * 8;
        a_ldst[it] = it * 2048 + w * 512;
    }
    size_t b_goff[2]; int b_ldst[2];
#pragma unroll
    for (int it = 0; it < 2; ++it) {
        int off = it * 4096 + w * 1024 + lane * 16;
        int row = off >> 7;
        int pg = (off >> 4) & 7;
        int lg = pg ^ (row & 7);
        b_goff[it] = (size_t)(n0 + row) * DMODEL + lg * 8;
        b_ldst[it] = it * 2048 + w * 512;
    }

    int aoff[2][2], boff[4][2];
#pragma unroll
    for (int mf = 0; mf < 2; ++mf)
#pragma unroll
        for (int ks = 0; ks < 2; ++ks) {
            int row = w * 32 + mf * 16 + (lane & 15);
            int g = ks * 4 + (lane >> 4);
            aoff[mf][ks] = row * 64 + ((g ^ (row & 7)) * 8);
        }
#pragma unroll
    for (int nf = 0; nf < 4; ++nf)
#pragma unroll
        for (int ks = 0; ks < 2; ++ks) {
            int row = nf * 16 + (lane & 15);
            int g = ks * 4 + (lane >> 4);
            boff[nf][ks] = row * 64 + ((g ^ (row & 7)) * 8);
        }

    f32x4 acc[2][4];
#pragma unroll
    for (int mf = 0; mf < 2; ++mf)
#pragma unroll
        for (int nf = 0; nf < 4; ++nf) acc[mf][nf] = (f32x4){0.f, 0.f, 0.f, 0.f};

#define STAGEG(BUF, KT) do {                                                  \
        int k0_ = (KT) * 64;                                                  \
        gl2lds16(Ah_g + a_goff[0] + k0_, &Ah[BUF][a_ldst[0]]);                \
        gl2lds16(Ah_g + a_goff[1] + k0_, &Ah[BUF][a_ldst[1]]);                \
        gl2lds16(Ah_g + a_goff[2] + k0_, &Ah[BUF][a_ldst[2]]);                \
        gl2lds16(Ah_g + a_goff[3] + k0_, &Ah[BUF][a_ldst[3]]);                \
        gl2lds16(Bh_g + b_goff[0] + k0_, &Bh[BUF][b_ldst[0]]);                \
        gl2lds16(Bh_g + b_goff[1] + k0_, &Bh[BUF][b_ldst[1]]);                \
    } while (0)

    STAGEG(0, 0);

    for (int kt = 0; kt < 16; ++kt) {
        const int cur = kt & 1;
        asm volatile("s_waitcnt vmcnt(0)" ::: "memory");
        __builtin_amdgcn_s_barrier();
        if (kt < 15) STAGEG(cur ^ 1, kt + 1);
#pragma unroll
        for (int ks = 0; ks < 2; ++ks) {
            bf16x8 ah[2], bh[4];
#pragma unroll
            for (int mf = 0; mf < 2; ++mf)
                ah[mf] = *reinterpret_cast<const bf16x8*>(&Ah[cur][aoff[mf][ks]]);
#pragma unroll
            for (int nf = 0; nf < 4; ++nf)
                bh[nf] = *reinterpret_cast<const bf16x8*>(&Bh[cur][boff[nf][ks]]);
#pragma unroll
            for (int mf = 0; mf < 2; ++mf)
#pragma unroll
                for (int nf = 0; nf < 4; ++nf)
                    acc[mf][nf] = __builtin_amdgcn_mfma_f32_16x16x32_bf16(ah[mf], bh[nf], acc[mf][nf], 0, 0, 0);
        }
    }
#undef STAGEG

    const int c = lane & 15;
    const int rq = lane >> 4;
    float bv[4];
#pragma unroll
    for (int nf = 0; nf < 4; ++nf) bv[nf] = bias[n0 + nf * 16 + c];

#pragma unroll
    for (int mf = 0; mf < 2; ++mf) {
        int mbase = m0 + w * 32 + mf * 16 + rq * 4;
        if (MODE == 0) {
#pragma unroll
            for (int nf = 0; nf < 4; ++nf)
#pragma unroll
                for (int r = 0; r < 4; ++r)
                    Cf[(size_t)(mbase + r) * DMODEL + n0 + nf * 16 + c] = acc[mf][nf][r] + bv[nf];
        } else if (MODE == 1 || MODE == 2) {
#pragma unroll
            for (int r = 0; r < 4; ++r) {
                int m = mbase + r;
                int srow = m & (SEQ - 1);
                float x0 = acc[mf][0][r] + bv[0];
                float x1 = acc[mf][1][r] + bv[1];
                float x2 = acc[mf][2][r] + bv[2];
                float x3 = acc[mf][3][r] + bv[3];
                float s0 = sin_t[srow * 32 + c],      c0 = cos_t[srow * 32 + c];
                float s1 = sin_t[srow * 32 + 16 + c], c1 = cos_t[srow * 32 + 16 + c];
                float o0 = c0 * x0 - s0 * x2;
                float o2 = s0 * x0 + c0 * x2;
                float o1 = c1 * x1 - s1 * x3;
                float o3 = s1 * x1 + c1 * x3;
                if (MODE == 1) {
                    const float qs = 0.18033688011112042f;   // 0.125*log2(e)
                    o0 *= qs; o1 *= qs; o2 *= qs; o3 *= qs;
                }
                float ov[4] = { o0, o1, o2, o3 };
                size_t base = (size_t)m * DMODEL + n0 + c;
#pragma unroll
                for (int nf = 0; nf < 4; ++nf)
                    Ohi[base + nf * 16] = f2bf(ov[nf]);
            }
        } else {   // MODE 3: V^T [b,h,d,s]
            int bb = mbase >> 11;
            int s = mbase & (SEQ - 1);
            int h = n0 >> 6;
#pragma unroll
            for (int nf = 0; nf < 4; ++nf) {
                ushort4 h4;
                float v0 = acc[mf][nf][0] + bv[nf];
                float v1 = acc[mf][nf][1] + bv[nf];
                float v2 = acc[mf][nf][2] + bv[nf];
                float v3 = acc[mf][nf][3] + bv[nf];
                h4.x = f2bf(v0); h4.y = f2bf(v1); h4.z = f2bf(v2); h4.w = f2bf(v3);
                int d = nf * 16 + c;
                size_t o = ((size_t)((bb * NH + h) * KD + d)) * SEQ + s;
                *reinterpret_cast<ushort4*>(&Ohi[o]) = h4;
            }
        }
    }
}

// ---------------------------------------------------------------------------
// Flash attention, deferred-PV pipeline (unchanged from r11).
// ---------------------------------------------------------------------------
__global__ __launch_bounds__(256) void k_attn(const unsigned short* __restrict__ qhi,
                                              const unsigned short* __restrict__ khi,
                                              const unsigned short* __restrict__ vthi,
                                              unsigned short* __restrict__ ch) {
    __shared__ unsigned short Kh[2][64 * 64];
    __shared__ unsigned short Vh[3][64 * 64];   // [d][t], ring
    __shared__ unsigned short Ps[4][32 * 64];

    const int tid  = threadIdx.x;
    const int lane = tid & 63;
    const int w    = tid >> 6;                  // 0..3

    int bid = blockIdx.x;
    int wg  = (bid & 7) * 64 + (bid >> 3);      // 512 blocks, 8 XCD chunks
    const int qt = wg & 15;
    const int h  = (wg >> 4) & 15;
    const int b  = wg >> 8;
    const int q0 = qt * 128;

    bf16x8 qf[2][2];   // [mf][ks]
#pragma unroll
    for (int mf = 0; mf < 2; ++mf)
#pragma unroll
        for (int ks = 0; ks < 2; ++ks) {
            int row = q0 + w * 32 + mf * 16 + (lane & 15);
            int d = ks * 32 + (lane >> 4) * 8;
            qf[mf][ks] = *reinterpret_cast<const bf16x8*>(
                qhi + ((size_t)(b * SEQ + row) * NH + h) * KD + d);
        }

    size_t gK[2], gV[2]; int ld_[2];
#pragma unroll
    for (int it = 0; it < 2; ++it) {
        int off = it * 4096 + tid * 16;
        int row = off >> 7;
        int pg = (off >> 4) & 7;
        int lg = pg ^ (row & 7);
        gK[it] = ((size_t)(b * SEQ + row) * NH + h) * KD + lg * 8;
        gV[it] = ((size_t)(b * NH + h) * KD + row) * SEQ + lg * 8;
        ld_[it] = it * 2048 + w * 512;
    }

    f32x4 acc[2][4];
    float l_part[2] = { 0.f, 0.f };
#pragma unroll
    for (int mf = 0; mf < 2; ++mf)
#pragma unroll
        for (int nf = 0; nf < 4; ++nf) acc[mf][nf] = (f32x4){0.f, 0.f, 0.f, 0.f};

#define STAGE(KB, VB, TT) do {                                               \
        size_t kadv = (size_t)(TT) * 64 * NH * KD;                           \
        size_t vadv = (size_t)(TT) * 64;                                     \
        gl2lds16(khi  + gK[0] + kadv, &Kh[KB][ld_[0]]);                      \
        gl2lds16(khi  + gK[1] + kadv, &Kh[KB][ld_[1]]);                      \
        gl2lds16(vthi + gV[0] + vadv, &Vh[VB][ld_[0]]);                      \
        gl2lds16(vthi + gV[1] + vadv, &Vh[VB][ld_[1]]);                      \
    } while (0)

#define PV_STEP(VSRC) do {                                                   \
        _Pragma("unroll")                                                    \
        for (int ks = 0; ks < 2; ++ks) {                                     \
            bf16x8 pa[2];                                                    \
            _Pragma("unroll")                                                \
            for (int mf = 0; mf < 2; ++mf) {                                 \
                int prow = mf * 16 + (lane & 15);                            \
                int aoff = prow * 64 + (((ks * 4 + (lane >> 4)) ^ (prow & 7)) * 8); \
                pa[mf] = *reinterpret_cast<const bf16x8*>(&Ps[w][aoff]);     \
            }                                                                \
            _Pragma("unroll")                                                \
            for (int nf = 0; nf < 4; ++nf) {                                 \
                int drow = nf * 16 + (lane & 15);                            \
                int voff = drow * 64 + (((ks * 4 + (lane >> 4)) ^ (drow & 7)) * 8); \
                bf16x8 vf = *reinterpret_cast<const bf16x8*>(&Vh[VSRC][voff]); \
                _Pragma("unroll")                                            \
                for (int mf = 0; mf < 2; ++mf)                               \
                    acc[mf][nf] = __builtin_amdgcn_mfma_f32_16x16x32_bf16(pa[mf], vf, acc[mf][nf], 0, 0, 0); \
            }                                                                \
        }                                                                    \
    } while (0)

    STAGE(0, 0, 0);

    int vnext = 1;
    int vprev = 2;

    for (int t = 0; t < 32; ++t) {
        const int ck = t & 1;
        asm volatile("s_waitcnt vmcnt(0)" ::: "memory");
        __builtin_amdgcn_s_barrier();
        if (t < 31) STAGE(ck ^ 1, vnext, t + 1);

        __builtin_amdgcn_s_setprio(1);
        f32x4 s[2][4];
#pragma unroll
        for (int mf = 0; mf < 2; ++mf)
#pragma unroll
            for (int nf = 0; nf < 4; ++nf) s[mf][nf] = (f32x4){0.f, 0.f, 0.f, 0.f};
#pragma unroll
        for (int nf = 0; nf < 4; ++nf) {
#pragma unroll
            for (int ks = 0; ks < 2; ++ks) {
                int trow = nf * 16 + (lane & 15);
                int koff = trow * 64 + (((ks * 4 + (lane >> 4)) ^ (trow & 7)) * 8);
                bf16x8 kf = *reinterpret_cast<const bf16x8*>(&Kh[ck][koff]);
#pragma unroll
                for (int mf = 0; mf < 2; ++mf)
                    s[mf][nf] = __builtin_amdgcn_mfma_f32_16x16x32_bf16(kf, qf[mf][ks], s[mf][nf], 0, 0, 0);
            }
        }
        if (t > 0) PV_STEP(vprev);
        __builtin_amdgcn_s_setprio(0);

#pragma unroll
        for (int mf = 0; mf < 2; ++mf) {
            int qloc = mf * 16 + (lane & 15);
#pragma unroll
            for (int nf = 0; nf < 4; ++nf) {
                float p0 = exp2_hw(s[mf][nf][0]);
                float p1 = exp2_hw(s[mf][nf][1]);
                float p2 = exp2_hw(s[mf][nf][2]);
                float p3 = exp2_hw(s[mf][nf][3]);
                l_part[mf] += (p0 + p1) + (p2 + p3);
                unsigned w01 = cvt_pk_bf16(p0, p1);
                unsigned w23 = cvt_pk_bf16(p2, p3);
                int tb = nf * 16 + (lane >> 4) * 4;
                int phys = tb ^ ((qloc & 7) << 3);
                *reinterpret_cast<uint2*>(&Ps[w][qloc * 64 + phys]) = make_uint2(w01, w23);
            }
        }

        vnext = (vnext == 2) ? 0 : vnext + 1;
        vprev = (vprev == 2) ? 0 : vprev + 1;
    }

    PV_STEP(vprev);
#undef PV_STEP
#undef STAGE

#pragma unroll
    for (int mf = 0; mf < 2; ++mf) {
        l_part[mf] += __shfl_xor(l_part[mf], 16);
        l_part[mf] += __shfl_xor(l_part[mf], 32);
    }
#pragma unroll
    for (int mf = 0; mf < 2; ++mf) {
#pragma unroll
        for (int r = 0; r < 4; ++r) {
            float lsum = __shfl(l_part[mf], (lane >> 4) * 4 + r);
            float inv = 1.0f / lsum;
            int qg = q0 + w * 32 + mf * 16 + (lane >> 4) * 4 + r;
#pragma unroll
            for (int nf = 0; nf < 4; ++nf) {
                int d = nf * 16 + (lane & 15);
                float val = acc[mf][nf][r] * inv;
                ch[((size_t)(b * SEQ + qg) * NH + h) * KD + d] = f2bf(val);
            }
        }
    }
}

// ---------------------------------------------------------------------------
extern "C" void kernel_launch(void* const* d_in, const int* in_sizes, int n_in,
                              void* d_out, int out_size, void* d_ws, size_t ws_size,
                              hipStream_t stream) {
    const float* x  = (const float*)d_in[0];
    const float* Wq = (const float*)d_in[1];
    const float* bq = (const float*)d_in[2];
    const float* Wk = (const float*)d_in[3];
    const float* bk = (const float*)d_in[4];
    const float* Wv = (const float*)d_in[5];
    const float* bv = (const float*)d_in[6];
    const float* Wo = (const float*)d_in[7];
    const float* bo = (const float*)d_in[8];
    float* out = (float*)d_out;

    const size_t NE = (size_t)MROWS * DMODEL;   // 4M
    const size_t WE = (size_t)DMODEL * DMODEL;  // 1M
    float* ws    = (float*)d_ws;
    float* sin_t = ws;
    float* cos_t = sin_t + SEQ * 32;
    unsigned short* p = (unsigned short*)(cos_t + SEQ * 32);
    unsigned short* xh   = p; p += NE;
    unsigned short* qh_  = p; p += NE;
    unsigned short* kh_  = p; p += NE;
    unsigned short* vth  = p; p += NE;
    unsigned short* wth  = p; p += 4 * WE;   // hi pool: [Wq|Wk|Wv|Wo]^T
    unsigned short* ctxh = xh;   // alias: x dead after V projection

    k_rope_tables<<<(SEQ * 32 + 255) / 256, 256, 0, stream>>>(sin_t, cos_t);
    k_cvt_x<<<(int)(NE / 4 / 256), 256, 0, stream>>>(x, xh);
    k_cvt_w4<<<dim3(16, 16, 4), 256, 0, stream>>>(Wq, Wk, Wv, Wo, wth);

    k_mgemm<1><<<512, 256, 0, stream>>>(xh, wth + 0 * WE, bq, nullptr, qh_, sin_t, cos_t);
    k_mgemm<2><<<512, 256, 0, stream>>>(xh, wth + 1 * WE, bk, nullptr, kh_, sin_t, cos_t);
    k_mgemm<3><<<512, 256, 0, stream>>>(xh, wth + 2 * WE, bv, nullptr, vth, nullptr, nullptr);

    k_attn<<<512, 256, 0, stream>>>(qh_, kh_, vth, ctxh);

    k_mgemm<0><<<512, 256, 0, stream>>>(ctxh, wth + 3 * WE, bo, out, nullptr, nullptr, nullptr);
}

// Round 13
// 117.184 us; speedup vs baseline: 1.4943x; 1.1764x over previous
//
#include <hip/hip_runtime.h>
#include <math.h>

#define NH 16
#define KD 64
#define DMODEL 1024
#define BATCH 2
#define SEQ 2048
#define MROWS (BATCH*SEQ)

typedef float f32x4 __attribute__((ext_vector_type(4)));
typedef __bf16 bf16x8 __attribute__((ext_vector_type(8)));

__device__ __forceinline__ unsigned short f2bf(float x) {
    union { float f; unsigned u; } a; a.f = x;
    unsigned r = a.u + 0x7fffu + ((a.u >> 16) & 1u);
    return (unsigned short)(r >> 16);
}
__device__ __forceinline__ unsigned cvt_pk_bf16(float lo, float hi) {
    unsigned r;
    asm("v_cvt_pk_bf16_f32 %0, %1, %2" : "=v"(r) : "v"(lo), "v"(hi));
    return r;
}
__device__ __forceinline__ float exp2_hw(float x) {
    float r;
    asm("v_exp_f32 %0, %1" : "=v"(r) : "v"(x));
    return r;
}

__device__ __forceinline__ void gl2lds16(const void* gsrc, void* ldst) {
    __builtin_amdgcn_global_load_lds(
        (const __attribute__((address_space(1))) void*)gsrc,
        (__attribute__((address_space(3))) void*)ldst, 16, 0, 0);
}

// ---------------------------------------------------------------------------
// Fused prep: [0,256) rope tables; [256,4352) cvt_x; [4352,5376) cvt_w4.
// ---------------------------------------------------------------------------
__global__ __launch_bounds__(256) void k_prep(const float* __restrict__ x,
                                              const float* __restrict__ W0,
                                              const float* __restrict__ W1,
                                              const float* __restrict__ W2,
                                              const float* __restrict__ W3,
                                              float* __restrict__ sin_t,
                                              float* __restrict__ cos_t,
                                              unsigned short* __restrict__ xh,
                                              unsigned short* __restrict__ Th) {
    __shared__ float L[64][65];
    const int bid = blockIdx.x;
    const int tid = threadIdx.x;
    if (bid < 256) {
        int idx = bid * 256 + tid;
        int s = idx >> 5, i = idx & 31;
        float invf = expf((float)(2 * i) * (-logf(10000.0f) / (float)KD));
        float ang = (float)s * invf;
        sin_t[idx] = sinf(ang);
        cos_t[idx] = cosf(ang);
        return;
    }
    if (bid < 4352) {
        int idx = (bid - 256) * 256 + tid;
        float4 v = reinterpret_cast<const float4*>(x)[idx];
        ushort4 h;
        h.x = f2bf(v.x); h.y = f2bf(v.y); h.z = f2bf(v.z); h.w = f2bf(v.w);
        reinterpret_cast<ushort4*>(xh)[idx] = h;
        return;
    }
    // weight transpose+convert
    int r = bid - 4352;               // 0..1023
    int z = r >> 8;                   // weight id
    int rr = r & 255;
    const int n0 = (rr & 15) * 64, k0 = (rr >> 4) * 64;
    const float* W = (z == 0) ? W0 : (z == 1) ? W1 : (z == 2) ? W2 : W3;
    const size_t zoff = (size_t)z * DMODEL * DMODEL;
#pragma unroll
    for (int it = 0; it < 4; ++it) {
        int idx = tid + it * 256;
        int rw = idx >> 4;
        int c4 = (idx & 15) * 4;
        float4 v = *reinterpret_cast<const float4*>(&W[(size_t)(k0 + rw) * DMODEL + n0 + c4]);
        L[rw][c4 + 0] = v.x; L[rw][c4 + 1] = v.y; L[rw][c4 + 2] = v.z; L[rw][c4 + 3] = v.w;
    }
    __syncthreads();
    int rn = tid >> 2;
    int ks = (tid & 3) * 16;
#pragma unroll
    for (int g = 0; g < 4; ++g) {
        ushort4 h;
        h.x = f2bf(L[ks + g * 4 + 0][rn]);
        h.y = f2bf(L[ks + g * 4 + 1][rn]);
        h.z = f2bf(L[ks + g * 4 + 2][rn]);
        h.w = f2bf(L[ks + g * 4 + 3][rn]);
        size_t o = zoff + (size_t)(n0 + rn) * DMODEL + k0 + ks + g * 4;
        *reinterpret_cast<ushort4*>(&Th[o]) = h;
    }
}

// ---------------------------------------------------------------------------
// Fused QKV GEMM: plain bf16, dbuf, 1 barrier/kt. grid 1536 = z(Q,K,V) x 512.
// Tile 128x64, BK=64, 4 waves, LDS 48KB -> 3 blocks/CU.
// ---------------------------------------------------------------------------
__global__ __launch_bounds__(256) void k_mgemm_qkv(const unsigned short* __restrict__ Ah_g,
                                                   const unsigned short* __restrict__ Wp,
                                                   const float* __restrict__ bq,
                                                   const float* __restrict__ bk,
                                                   const float* __restrict__ bv,
                                                   unsigned short* __restrict__ qh_,
                                                   unsigned short* __restrict__ kh_,
                                                   unsigned short* __restrict__ vth,
                                                   const float* __restrict__ sin_t,
                                                   const float* __restrict__ cos_t) {
    __shared__ unsigned short Ah[2][128 * 64];
    __shared__ unsigned short Bh[2][64 * 64];
    const int tid = threadIdx.x;
    const int lane = tid & 63;
    const int w = tid >> 6;

    int bid = blockIdx.x;
    int wg = (bid & 7) * 192 + (bid >> 3);   // 1536 blocks, 8 XCD chunks
    const int z = wg >> 9;                    // 0=Q 1=K 2=V
    const int r = wg & 511;
    const int m0 = (r >> 4) * 128;
    const int n0 = (r & 15) * 64;
    const unsigned short* Bh_g = Wp + (size_t)z * DMODEL * DMODEL;
    const float* bias = (z == 0) ? bq : (z == 1) ? bk : bv;

    size_t a_goff[4]; int a_ldst[4];
#pragma unroll
    for (int it = 0; it < 4; ++it) {
        int off = it * 4096 + w * 1024 + lane * 16;
        int row = off >> 7;
        int pg = (off >> 4) & 7;
        int lg = pg ^ (row & 7);
        a_goff[it] = (size_t)(m0 + row) * DMODEL + lg * 8;
        a_ldst[it] = it * 2048 + w * 512;
    }
    size_t b_goff[2]; int b_ldst[2];
#pragma unroll
    for (int it = 0; it < 2; ++it) {
        int off = it * 4096 + w * 1024 + lane * 16;
        int row = off >> 7;
        int pg = (off >> 4) & 7;
        int lg = pg ^ (row & 7);
        b_goff[it] = (size_t)(n0 + row) * DMODEL + lg * 8;
        b_ldst[it] = it * 2048 + w * 512;
    }

    int aoff[2][2], boff[4][2];
#pragma unroll
    for (int mf = 0; mf < 2; ++mf)
#pragma unroll
        for (int ks = 0; ks < 2; ++ks) {
            int row = w * 32 + mf * 16 + (lane & 15);
            int g = ks * 4 + (lane >> 4);
            aoff[mf][ks] = row * 64 + ((g ^ (row & 7)) * 8);
        }
#pragma unroll
    for (int nf = 0; nf < 4; ++nf)
#pragma unroll
        for (int ks = 0; ks < 2; ++ks) {
            int row = nf * 16 + (lane & 15);
            int g = ks * 4 + (lane >> 4);
            boff[nf][ks] = row * 64 + ((g ^ (row & 7)) * 8);
        }

    f32x4 acc[2][4];
#pragma unroll
    for (int mf = 0; mf < 2; ++mf)
#pragma unroll
        for (int nf = 0; nf < 4; ++nf) acc[mf][nf] = (f32x4){0.f, 0.f, 0.f, 0.f};

#define STAGEG(BUF, KT) do {                                                  \
        int k0_ = (KT) * 64;                                                  \
        gl2lds16(Ah_g + a_goff[0] + k0_, &Ah[BUF][a_ldst[0]]);                \
        gl2lds16(Ah_g + a_goff[1] + k0_, &Ah[BUF][a_ldst[1]]);                \
        gl2lds16(Ah_g + a_goff[2] + k0_, &Ah[BUF][a_ldst[2]]);                \
        gl2lds16(Ah_g + a_goff[3] + k0_, &Ah[BUF][a_ldst[3]]);                \
        gl2lds16(Bh_g + b_goff[0] + k0_, &Bh[BUF][b_ldst[0]]);                \
        gl2lds16(Bh_g + b_goff[1] + k0_, &Bh[BUF][b_ldst[1]]);                \
    } while (0)

    STAGEG(0, 0);

    for (int kt = 0; kt < 16; ++kt) {
        const int cur = kt & 1;
        asm volatile("s_waitcnt vmcnt(0)" ::: "memory");
        __builtin_amdgcn_s_barrier();
        if (kt < 15) STAGEG(cur ^ 1, kt + 1);
#pragma unroll
        for (int ks = 0; ks < 2; ++ks) {
            bf16x8 ah[2], bh[4];
#pragma unroll
            for (int mf = 0; mf < 2; ++mf)
                ah[mf] = *reinterpret_cast<const bf16x8*>(&Ah[cur][aoff[mf][ks]]);
#pragma unroll
            for (int nf = 0; nf < 4; ++nf)
                bh[nf] = *reinterpret_cast<const bf16x8*>(&Bh[cur][boff[nf][ks]]);
#pragma unroll
            for (int mf = 0; mf < 2; ++mf)
#pragma unroll
                for (int nf = 0; nf < 4; ++nf)
                    acc[mf][nf] = __builtin_amdgcn_mfma_f32_16x16x32_bf16(ah[mf], bh[nf], acc[mf][nf], 0, 0, 0);
        }
    }
#undef STAGEG

    const int c = lane & 15;
    const int rq = lane >> 4;
    float bv_[4];
#pragma unroll
    for (int nf = 0; nf < 4; ++nf) bv_[nf] = bias[n0 + nf * 16 + c];

#pragma unroll
    for (int mf = 0; mf < 2; ++mf) {
        int mbase = m0 + w * 32 + mf * 16 + rq * 4;
        if (z < 2) {
#pragma unroll
            for (int r2 = 0; r2 < 4; ++r2) {
                int m = mbase + r2;
                int srow = m & (SEQ - 1);
                float x0 = acc[mf][0][r2] + bv_[0];
                float x1 = acc[mf][1][r2] + bv_[1];
                float x2 = acc[mf][2][r2] + bv_[2];
                float x3 = acc[mf][3][r2] + bv_[3];
                float s0 = sin_t[srow * 32 + c],      c0 = cos_t[srow * 32 + c];
                float s1 = sin_t[srow * 32 + 16 + c], c1 = cos_t[srow * 32 + 16 + c];
                float o0 = c0 * x0 - s0 * x2;
                float o2 = s0 * x0 + c0 * x2;
                float o1 = c1 * x1 - s1 * x3;
                float o3 = s1 * x1 + c1 * x3;
                unsigned short* Ohi = kh_;
                if (z == 0) {
                    const float qs = 0.18033688011112042f;   // 0.125*log2(e)
                    o0 *= qs; o1 *= qs; o2 *= qs; o3 *= qs;
                    Ohi = qh_;
                }
                float ov[4] = { o0, o1, o2, o3 };
                size_t base = (size_t)m * DMODEL + n0 + c;
#pragma unroll
                for (int nf = 0; nf < 4; ++nf)
                    Ohi[base + nf * 16] = f2bf(ov[nf]);
            }
        } else {   // V^T [b,h,d,s]
            int bb = mbase >> 11;
            int s = mbase & (SEQ - 1);
            int h = n0 >> 6;
#pragma unroll
            for (int nf = 0; nf < 4; ++nf) {
                ushort4 h4;
                float v0 = acc[mf][nf][0] + bv_[nf];
                float v1 = acc[mf][nf][1] + bv_[nf];
                float v2 = acc[mf][nf][2] + bv_[nf];
                float v3 = acc[mf][nf][3] + bv_[nf];
                h4.x = f2bf(v0); h4.y = f2bf(v1); h4.z = f2bf(v2); h4.w = f2bf(v3);
                int d = nf * 16 + c;
                size_t o = ((size_t)((bb * NH + h) * KD + d)) * SEQ + s;
                *reinterpret_cast<ushort4*>(&vth[o]) = h4;
            }
        }
    }
}

// ---------------------------------------------------------------------------
// O-projection GEMM: plain bf16, dbuf, 1 barrier/kt, fp32+bias out. 512 blocks.
// ---------------------------------------------------------------------------
__global__ __launch_bounds__(256) void k_mgemm_o(const unsigned short* __restrict__ Ah_g,
                                                 const unsigned short* __restrict__ Bh_g,
                                                 const float* __restrict__ bias,
                                                 float* __restrict__ Cf) {
    __shared__ unsigned short Ah[2][128 * 64];
    __shared__ unsigned short Bh[2][64 * 64];
    const int tid = threadIdx.x;
    const int lane = tid & 63;
    const int w = tid >> 6;

    int bid = blockIdx.x;
    int wg = (bid & 7) * 64 + (bid >> 3);
    const int m0 = (wg >> 4) * 128;
    const int n0 = (wg & 15) * 64;

    size_t a_goff[4]; int a_ldst[4];
#pragma unroll
    for (int it = 0; it < 4; ++it) {
        int off = it * 4096 + w * 1024 + lane * 16;
        int row = off >> 7;
        int pg = (off >> 4) & 7;
        int lg = pg ^ (row & 7);
        a_goff[it] = (size_t)(m0 + row) * DMODEL + lg * 8;
        a_ldst[it] = it * 2048 + w * 512;
    }
    size_t b_goff[2]; int b_ldst[2];
#pragma unroll
    for (int it = 0; it < 2; ++it) {
        int off = it * 4096 + w * 1024 + lane * 16;
        int row = off >> 7;
        int pg = (off >> 4) & 7;
        int lg = pg ^ (row & 7);
        b_goff[it] = (size_t)(n0 + row) * DMODEL + lg * 8;
        b_ldst[it] = it * 2048 + w * 512;
    }

    int aoff[2][2], boff[4][2];
#pragma unroll
    for (int mf = 0; mf < 2; ++mf)
#pragma unroll
        for (int ks = 0; ks < 2; ++ks) {
            int row = w * 32 + mf * 16 + (lane & 15);
            int g = ks * 4 + (lane >> 4);
            aoff[mf][ks] = row * 64 + ((g ^ (row & 7)) * 8);
        }
#pragma unroll
    for (int nf = 0; nf < 4; ++nf)
#pragma unroll
        for (int ks = 0; ks < 2; ++ks) {
            int row = nf * 16 + (lane & 15);
            int g = ks * 4 + (lane >> 4);
            boff[nf][ks] = row * 64 + ((g ^ (row & 7)) * 8);
        }

    f32x4 acc[2][4];
#pragma unroll
    for (int mf = 0; mf < 2; ++mf)
#pragma unroll
        for (int nf = 0; nf < 4; ++nf) acc[mf][nf] = (f32x4){0.f, 0.f, 0.f, 0.f};

#define STAGEG(BUF, KT) do {                                                  \
        int k0_ = (KT) * 64;                                                  \
        gl2lds16(Ah_g + a_goff[0] + k0_, &Ah[BUF][a_ldst[0]]);                \
        gl2lds16(Ah_g + a_goff[1] + k0_, &Ah[BUF][a_ldst[1]]);                \
        gl2lds16(Ah_g + a_goff[2] + k0_, &Ah[BUF][a_ldst[2]]);                \
        gl2lds16(Ah_g + a_goff[3] + k0_, &Ah[BUF][a_ldst[3]]);                \
        gl2lds16(Bh_g + b_goff[0] + k0_, &Bh[BUF][b_ldst[0]]);                \
        gl2lds16(Bh_g + b_goff[1] + k0_, &Bh[BUF][b_ldst[1]]);                \
    } while (0)

    STAGEG(0, 0);

    for (int kt = 0; kt < 16; ++kt) {
        const int cur = kt & 1;
        asm volatile("s_waitcnt vmcnt(0)" ::: "memory");
        __builtin_amdgcn_s_barrier();
        if (kt < 15) STAGEG(cur ^ 1, kt + 1);
#pragma unroll
        for (int ks = 0; ks < 2; ++ks) {
            bf16x8 ah[2], bh[4];
#pragma unroll
            for (int mf = 0; mf < 2; ++mf)
                ah[mf] = *reinterpret_cast<const bf16x8*>(&Ah[cur][aoff[mf][ks]]);
#pragma unroll
            for (int nf = 0; nf < 4; ++nf)
                bh[nf] = *reinterpret_cast<const bf16x8*>(&Bh[cur][boff[nf][ks]]);
#pragma unroll
            for (int mf = 0; mf < 2; ++mf)
#pragma unroll
                for (int nf = 0; nf < 4; ++nf)
                    acc[mf][nf] = __builtin_amdgcn_mfma_f32_16x16x32_bf16(ah[mf], bh[nf], acc[mf][nf], 0, 0, 0);
        }
    }
#undef STAGEG

    const int c = lane & 15;
    const int rq = lane >> 4;
    float bv[4];
#pragma unroll
    for (int nf = 0; nf < 4; ++nf) bv[nf] = bias[n0 + nf * 16 + c];
#pragma unroll
    for (int mf = 0; mf < 2; ++mf) {
        int mbase = m0 + w * 32 + mf * 16 + rq * 4;
#pragma unroll
        for (int nf = 0; nf < 4; ++nf)
#pragma unroll
            for (int r = 0; r < 4; ++r)
                Cf[(size_t)(mbase + r) * DMODEL + n0 + nf * 16 + c] = acc[mf][nf][r] + bv[nf];
    }
}

// ---------------------------------------------------------------------------
// Flash attention, deferred-PV pipeline (unchanged from r12).
// ---------------------------------------------------------------------------
__global__ __launch_bounds__(256) void k_attn(const unsigned short* __restrict__ qhi,
                                              const unsigned short* __restrict__ khi,
                                              const unsigned short* __restrict__ vthi,
                                              unsigned short* __restrict__ ch) {
    __shared__ unsigned short Kh[2][64 * 64];
    __shared__ unsigned short Vh[3][64 * 64];   // [d][t], ring
    __shared__ unsigned short Ps[4][32 * 64];

    const int tid  = threadIdx.x;
    const int lane = tid & 63;
    const int w    = tid >> 6;                  // 0..3

    int bid = blockIdx.x;
    int wg  = (bid & 7) * 64 + (bid >> 3);      // 512 blocks, 8 XCD chunks
    const int qt = wg & 15;
    const int h  = (wg >> 4) & 15;
    const int b  = wg >> 8;
    const int q0 = qt * 128;

    bf16x8 qf[2][2];   // [mf][ks]
#pragma unroll
    for (int mf = 0; mf < 2; ++mf)
#pragma unroll
        for (int ks = 0; ks < 2; ++ks) {
            int row = q0 + w * 32 + mf * 16 + (lane & 15);
            int d = ks * 32 + (lane >> 4) * 8;
            qf[mf][ks] = *reinterpret_cast<const bf16x8*>(
                qhi + ((size_t)(b * SEQ + row) * NH + h) * KD + d);
        }

    size_t gK[2], gV[2]; int ld_[2];
#pragma unroll
    for (int it = 0; it < 2; ++it) {
        int off = it * 4096 + tid * 16;
        int row = off >> 7;
        int pg = (off >> 4) & 7;
        int lg = pg ^ (row & 7);
        gK[it] = ((size_t)(b * SEQ + row) * NH + h) * KD + lg * 8;
        gV[it] = ((size_t)(b * NH + h) * KD + row) * SEQ + lg * 8;
        ld_[it] = it * 2048 + w * 512;
    }

    f32x4 acc[2][4];
    float l_part[2] = { 0.f, 0.f };
#pragma unroll
    for (int mf = 0; mf < 2; ++mf)
#pragma unroll
        for (int nf = 0; nf < 4; ++nf) acc[mf][nf] = (f32x4){0.f, 0.f, 0.f, 0.f};

#define STAGE(KB, VB, TT) do {                                               \
        size_t kadv = (size_t)(TT) * 64 * NH * KD;                           \
        size_t vadv = (size_t)(TT) * 64;                                     \
        gl2lds16(khi  + gK[0] + kadv, &Kh[KB][ld_[0]]);                      \
        gl2lds16(khi  + gK[1] + kadv, &Kh[KB][ld_[1]]);                      \
        gl2lds16(vthi + gV[0] + vadv, &Vh[VB][ld_[0]]);                      \
        gl2lds16(vthi + gV[1] + vadv, &Vh[VB][ld_[1]]);                      \
    } while (0)

#define PV_STEP(VSRC) do {                                                   \
        _Pragma("unroll")                                                    \
        for (int ks = 0; ks < 2; ++ks) {                                     \
            bf16x8 pa[2];                                                    \
            _Pragma("unroll")                                                \
            for (int mf = 0; mf < 2; ++mf) {                                 \
                int prow = mf * 16 + (lane & 15);                            \
                int aoff = prow * 64 + (((ks * 4 + (lane >> 4)) ^ (prow & 7)) * 8); \
                pa[mf] = *reinterpret_cast<const bf16x8*>(&Ps[w][aoff]);     \
            }                                                                \
            _Pragma("unroll")                                                \
            for (int nf = 0; nf < 4; ++nf) {                                 \
                int drow = nf * 16 + (lane & 15);                            \
                int voff = drow * 64 + (((ks * 4 + (lane >> 4)) ^ (drow & 7)) * 8); \
                bf16x8 vf = *reinterpret_cast<const bf16x8*>(&Vh[VSRC][voff]); \
                _Pragma("unroll")                                            \
                for (int mf = 0; mf < 2; ++mf)                               \
                    acc[mf][nf] = __builtin_amdgcn_mfma_f32_16x16x32_bf16(pa[mf], vf, acc[mf][nf], 0, 0, 0); \
            }                                                                \
        }                                                                    \
    } while (0)

    STAGE(0, 0, 0);

    int vnext = 1;
    int vprev = 2;

    for (int t = 0; t < 32; ++t) {
        const int ck = t & 1;
        asm volatile("s_waitcnt vmcnt(0)" ::: "memory");
        __builtin_amdgcn_s_barrier();
        if (t < 31) STAGE(ck ^ 1, vnext, t + 1);

        __builtin_amdgcn_s_setprio(1);
        f32x4 s[2][4];
#pragma unroll
        for (int mf = 0; mf < 2; ++mf)
#pragma unroll
            for (int nf = 0; nf < 4; ++nf) s[mf][nf] = (f32x4){0.f, 0.f, 0.f, 0.f};
#pragma unroll
        for (int nf = 0; nf < 4; ++nf) {
#pragma unroll
            for (int ks = 0; ks < 2; ++ks) {
                int trow = nf * 16 + (lane & 15);
                int koff = trow * 64 + (((ks * 4 + (lane >> 4)) ^ (trow & 7)) * 8);
                bf16x8 kf = *reinterpret_cast<const bf16x8*>(&Kh[ck][koff]);
#pragma unroll
                for (int mf = 0; mf < 2; ++mf)
                    s[mf][nf] = __builtin_amdgcn_mfma_f32_16x16x32_bf16(kf, qf[mf][ks], s[mf][nf], 0, 0, 0);
            }
        }
        if (t > 0) PV_STEP(vprev);
        __builtin_amdgcn_s_setprio(0);

#pragma unroll
        for (int mf = 0; mf < 2; ++mf) {
            int qloc = mf * 16 + (lane & 15);
#pragma unroll
            for (int nf = 0; nf < 4; ++nf) {
                float p0 = exp2_hw(s[mf][nf][0]);
                float p1 = exp2_hw(s[mf][nf][1]);
                float p2 = exp2_hw(s[mf][nf][2]);
                float p3 = exp2_hw(s[mf][nf][3]);
                l_part[mf] += (p0 + p1) + (p2 + p3);
                unsigned w01 = cvt_pk_bf16(p0, p1);
                unsigned w23 = cvt_pk_bf16(p2, p3);
                int tb = nf * 16 + (lane >> 4) * 4;
                int phys = tb ^ ((qloc & 7) << 3);
                *reinterpret_cast<uint2*>(&Ps[w][qloc * 64 + phys]) = make_uint2(w01, w23);
            }
        }

        vnext = (vnext == 2) ? 0 : vnext + 1;
        vprev = (vprev == 2) ? 0 : vprev + 1;
    }

    PV_STEP(vprev);
#undef PV_STEP
#undef STAGE

#pragma unroll
    for (int mf = 0; mf < 2; ++mf) {
        l_part[mf] += __shfl_xor(l_part[mf], 16);
        l_part[mf] += __shfl_xor(l_part[mf], 32);
    }
#pragma unroll
    for (int mf = 0; mf < 2; ++mf) {
#pragma unroll
        for (int r = 0; r < 4; ++r) {
            float lsum = __shfl(l_part[mf], (lane >> 4) * 4 + r);
            float inv = 1.0f / lsum;
            int qg = q0 + w * 32 + mf * 16 + (lane >> 4) * 4 + r;
#pragma unroll
            for (int nf = 0; nf < 4; ++nf) {
                int d = nf * 16 + (lane & 15);
                float val = acc[mf][nf][r] * inv;
                ch[((size_t)(b * SEQ + qg) * NH + h) * KD + d] = f2bf(val);
            }
        }
    }
}

// ---------------------------------------------------------------------------
extern "C" void kernel_launch(void* const* d_in, const int* in_sizes, int n_in,
                              void* d_out, int out_size, void* d_ws, size_t ws_size,
                              hipStream_t stream) {
    const float* x  = (const float*)d_in[0];
    const float* Wq = (const float*)d_in[1];
    const float* bq = (const float*)d_in[2];
    const float* Wk = (const float*)d_in[3];
    const float* bk = (const float*)d_in[4];
    const float* Wv = (const float*)d_in[5];
    const float* bv = (const float*)d_in[6];
    const float* Wo = (const float*)d_in[7];
    const float* bo = (const float*)d_in[8];
    float* out = (float*)d_out;

    const size_t NE = (size_t)MROWS * DMODEL;   // 4M
    const size_t WE = (size_t)DMODEL * DMODEL;  // 1M
    float* ws    = (float*)d_ws;
    float* sin_t = ws;
    float* cos_t = sin_t + SEQ * 32;
    unsigned short* p = (unsigned short*)(cos_t + SEQ * 32);
    unsigned short* xh   = p; p += NE;
    unsigned short* qh_  = p; p += NE;
    unsigned short* kh_  = p; p += NE;
    unsigned short* vth  = p; p += NE;
    unsigned short* wth  = p; p += 4 * WE;   // hi pool: [Wq|Wk|Wv|Wo]^T
    unsigned short* ctxh = xh;   // alias: x dead after V projection

    k_prep<<<5376, 256, 0, stream>>>(x, Wq, Wk, Wv, Wo, sin_t, cos_t, xh, wth);

    k_mgemm_qkv<<<1536, 256, 0, stream>>>(xh, wth, bq, bk, bv, qh_, kh_, vth, sin_t, cos_t);

    k_attn<<<512, 256, 0, stream>>>(qh_, kh_, vth, ctxh);

    k_mgemm_o<<<512, 256, 0, stream>>>(ctxh, wth + 3 * WE, bo, out);
}